// Round 1
// baseline (683.786 us; speedup 1.0000x reference)
//
#include <hip/hip_runtime.h>
#include <hip/hip_bf16.h>
#include <math.h>

typedef __attribute__((ext_vector_type(4))) float f4_t;
typedef __attribute__((ext_vector_type(8))) short s8_t;

// Problem constants
constexpr int Bc = 64;      // batches
constexpr int Tc = 1024;    // tokens per batch (H*W)
constexpr int Cc = 512;     // channels
constexpr int Ec = 5;       // experts
constexpr int HIDc = 2048;  // hidden

// ---------------- gating ----------------

// partial sums over token sub-ranges: part[b][p][c] = sum_{t in p-th 128} x[b][t][c]
__global__ void k_partial(const float* __restrict__ x, float* __restrict__ part) {
  int b = blockIdx.x, p = blockIdx.y, tid = threadIdx.x;
  const float* xp = x + ((size_t)b * Tc + (size_t)p * 128) * Cc;
  float s0 = 0.f, s1 = 0.f;
  for (int t = 0; t < 128; ++t) {
    s0 += xp[(size_t)t * Cc + tid];
    s1 += xp[(size_t)t * Cc + tid + 256];
  }
  part[(size_t)(b * 8 + p) * Cc + tid] = s0;
  part[(size_t)(b * 8 + p) * Cc + tid + 256] = s1;
}

// per-batch: finalize xg (mean) in LDS, compute logits[b][e]
__global__ void k_xg_logits(const float* __restrict__ part, const float* __restrict__ wg,
                            float* __restrict__ logits) {
  __shared__ float xg[Cc];
  __shared__ float red[Ec][4];
  int b = blockIdx.x, tid = threadIdx.x;
  for (int c = tid; c < Cc; c += 256) {
    float s = 0.f;
#pragma unroll
    for (int p = 0; p < 8; ++p) s += part[(size_t)(b * 8 + p) * Cc + c];
    xg[c] = s * (1.0f / 1024.0f);
  }
  __syncthreads();
  float le[Ec] = {0.f, 0.f, 0.f, 0.f, 0.f};
  for (int c = tid; c < Cc; c += 256) {
    float v = xg[c];
#pragma unroll
    for (int e = 0; e < Ec; ++e) le[e] += v * wg[c * Ec + e];
  }
#pragma unroll
  for (int e = 0; e < Ec; ++e) {
    float v = le[e];
#pragma unroll
    for (int off = 32; off > 0; off >>= 1) v += __shfl_down(v, off);
    if ((tid & 63) == 0) red[e][tid >> 6] = v;
  }
  __syncthreads();
  if (tid < Ec) {
    float v = red[tid][0] + red[tid][1] + red[tid][2] + red[tid][3];
    v = fminf(fmaxf(v, -50.f), 50.f);
    logits[b * Ec + tid] = v;
  }
}

// argmax per batch, counts, loss
__global__ void k_gate(const float* __restrict__ logits, int* __restrict__ idx,
                       float* __restrict__ loss_out) {
  __shared__ int cnt[Ec];
  int tid = threadIdx.x;
  if (tid < Ec) cnt[tid] = 0;
  __syncthreads();
  if (tid < Bc) {
    const float* lb = logits + tid * Ec;
    int best = 0;
    float bv = lb[0];
#pragma unroll
    for (int e = 1; e < Ec; ++e) {
      float v = lb[e];
      if (v > bv) { bv = v; best = e; }
    }
    idx[tid] = best;
    atomicAdd(&cnt[best], 1);
  }
  __syncthreads();
  if (tid == 0) {
    const float mean = (float)Bc / (float)Ec;  // 12.8
    float var = 0.f;
#pragma unroll
    for (int e = 0; e < Ec; ++e) {
      float d = (float)cnt[e] - mean;
      var += d * d;
    }
    var *= (1.0f / (Ec - 1));
    float loss = 2.f * (var / (mean * mean + 1e-10f));
    loss = fminf(fmaxf(loss, 0.f), 1000.f);
    *loss_out = loss;
  }
}

// ---------------- weight transpose-convert: src (E,K,N) f32 -> dst (E,N,K) bf16 ----------------
__global__ void k_transpose_cvt(const float* __restrict__ src, __hip_bfloat16* __restrict__ dst,
                                int K, int N) {
  __shared__ float tile[32][33];
  int e = blockIdx.z;
  int kb = blockIdx.y * 32, nb = blockIdx.x * 32;
  const float* s = src + (size_t)e * K * N;
  __hip_bfloat16* d = dst + (size_t)e * K * N;
  int lx = threadIdx.x & 31, ly = threadIdx.x >> 5;  // ly: 0..7
#pragma unroll
  for (int r = 0; r < 4; ++r) {
    int k = kb + ly + r * 8;
    tile[ly + r * 8][lx] = s[(size_t)k * N + nb + lx];
  }
  __syncthreads();
#pragma unroll
  for (int r = 0; r < 4; ++r) {
    int n = nb + ly + r * 8;
    d[(size_t)n * K + kb + lx] = __float2bfloat16(tile[lx][ly + r * 8]);
  }
}

// ---------------- x fp32 -> bf16 ----------------
__global__ void k_cvt_x(const float* __restrict__ src, ushort* __restrict__ dst, int n4) {
  int i = blockIdx.x * blockDim.x + threadIdx.x;
  int stride = gridDim.x * blockDim.x;
  const float4* s4 = (const float4*)src;
  ushort4* d4 = (ushort4*)dst;
  for (; i < n4; i += stride) {
    float4 v = s4[i];
    union { __hip_bfloat16 h[4]; ushort4 u; } cv;
    cv.h[0] = __float2bfloat16(v.x);
    cv.h[1] = __float2bfloat16(v.y);
    cv.h[2] = __float2bfloat16(v.z);
    cv.h[3] = __float2bfloat16(v.w);
    d4[i] = cv.u;
  }
}

// ---------------- GEMM1: h = gelu(x @ W1[e] + b1[e]), bf16 out ----------------
// A: xbf [cb][1024][512] (M x K row-major), B: w1t [E][2048][512] (N x K row-major)
__global__ __launch_bounds__(256) void k_gemm1(
    const __hip_bfloat16* __restrict__ xbf, const __hip_bfloat16* __restrict__ w1t,
    const float* __restrict__ b1, const int* __restrict__ idx, int b0,
    __hip_bfloat16* __restrict__ h) {
  constexpr int K = Cc;     // 512
  constexpr int N = HIDc;   // 2048
  __shared__ short As[128 * 32];
  __shared__ short Bs[128 * 32];
  int bz = blockIdx.z;
  int e = idx[b0 + bz];
  int m0 = blockIdx.y * 128;
  int n0 = blockIdx.x * 128;
  const short* Abase = (const short*)(xbf + (size_t)bz * Tc * K) + (size_t)m0 * K;
  const short* Bbase = (const short*)(w1t + (size_t)e * N * K) + (size_t)n0 * K;
  int tid = threadIdx.x;
  int lane = tid & 63, wv = tid >> 6;
  int wr = wv >> 1, wc = wv & 1;
  int c0 = tid, c1 = tid + 256;

  f4_t acc[4][4] = {};

  for (int k0 = 0; k0 < K; k0 += 32) {
    __syncthreads();
    *(s8_t*)(As + c0 * 8) = *(const s8_t*)(Abase + (size_t)(c0 >> 2) * K + k0 + ((c0 & 3) << 3));
    *(s8_t*)(As + c1 * 8) = *(const s8_t*)(Abase + (size_t)(c1 >> 2) * K + k0 + ((c1 & 3) << 3));
    *(s8_t*)(Bs + c0 * 8) = *(const s8_t*)(Bbase + (size_t)(c0 >> 2) * K + k0 + ((c0 & 3) << 3));
    *(s8_t*)(Bs + c1 * 8) = *(const s8_t*)(Bbase + (size_t)(c1 >> 2) * K + k0 + ((c1 & 3) << 3));
    __syncthreads();
    s8_t a[4], b[4];
#pragma unroll
    for (int f = 0; f < 4; ++f)
      a[f] = *(const s8_t*)(As + (wr * 64 + f * 16 + (lane & 15)) * 32 + ((lane >> 4) << 3));
#pragma unroll
    for (int f = 0; f < 4; ++f)
      b[f] = *(const s8_t*)(Bs + (wc * 64 + f * 16 + (lane & 15)) * 32 + ((lane >> 4) << 3));
#pragma unroll
    for (int fm = 0; fm < 4; ++fm)
#pragma unroll
      for (int fn = 0; fn < 4; ++fn)
        acc[fm][fn] = __builtin_amdgcn_mfma_f32_16x16x32_bf16(a[fm], b[fn], acc[fm][fn], 0, 0, 0);
  }

  __hip_bfloat16* hb = h + (size_t)bz * Tc * N;
  const float* bias = b1 + (size_t)e * N;
#pragma unroll
  for (int fn = 0; fn < 4; ++fn) {
    int col = n0 + wc * 64 + fn * 16 + (lane & 15);
    float bv = bias[col];
#pragma unroll
    for (int fm = 0; fm < 4; ++fm) {
      int rbase = m0 + wr * 64 + fm * 16 + ((lane >> 4) << 2);
#pragma unroll
      for (int r = 0; r < 4; ++r) {
        float v = acc[fm][fn][r] + bv;
        v = 0.5f * v * (1.0f + erff(v * 0.70710678118654752f));
        hb[(size_t)(rbase + r) * N + col] = __float2bfloat16(v);
      }
    }
  }
}

// ---------------- GEMM2: y = h @ W2[e] + b2[e], fp32 out ----------------
// A: h [cb][1024][2048] (M x K row-major), B: w2t [E][512][2048] (N x K row-major)
__global__ __launch_bounds__(256) void k_gemm2(
    const __hip_bfloat16* __restrict__ h, const __hip_bfloat16* __restrict__ w2t,
    const float* __restrict__ b2, const int* __restrict__ idx, int b0,
    float* __restrict__ out) {
  constexpr int K = HIDc;  // 2048
  constexpr int N = Cc;    // 512
  __shared__ short As[128 * 32];
  __shared__ short Bs[128 * 32];
  int bz = blockIdx.z;
  int e = idx[b0 + bz];
  int m0 = blockIdx.y * 128;
  int n0 = blockIdx.x * 128;
  const short* Abase = (const short*)(h + (size_t)bz * Tc * K) + (size_t)m0 * K;
  const short* Bbase = (const short*)(w2t + (size_t)e * (size_t)N * K) + (size_t)n0 * K;
  int tid = threadIdx.x;
  int lane = tid & 63, wv = tid >> 6;
  int wr = wv >> 1, wc = wv & 1;
  int c0 = tid, c1 = tid + 256;

  f4_t acc[4][4] = {};

  for (int k0 = 0; k0 < K; k0 += 32) {
    __syncthreads();
    *(s8_t*)(As + c0 * 8) = *(const s8_t*)(Abase + (size_t)(c0 >> 2) * K + k0 + ((c0 & 3) << 3));
    *(s8_t*)(As + c1 * 8) = *(const s8_t*)(Abase + (size_t)(c1 >> 2) * K + k0 + ((c1 & 3) << 3));
    *(s8_t*)(Bs + c0 * 8) = *(const s8_t*)(Bbase + (size_t)(c0 >> 2) * K + k0 + ((c0 & 3) << 3));
    *(s8_t*)(Bs + c1 * 8) = *(const s8_t*)(Bbase + (size_t)(c1 >> 2) * K + k0 + ((c1 & 3) << 3));
    __syncthreads();
    s8_t a[4], b[4];
#pragma unroll
    for (int f = 0; f < 4; ++f)
      a[f] = *(const s8_t*)(As + (wr * 64 + f * 16 + (lane & 15)) * 32 + ((lane >> 4) << 3));
#pragma unroll
    for (int f = 0; f < 4; ++f)
      b[f] = *(const s8_t*)(Bs + (wc * 64 + f * 16 + (lane & 15)) * 32 + ((lane >> 4) << 3));
#pragma unroll
    for (int fm = 0; fm < 4; ++fm)
#pragma unroll
      for (int fn = 0; fn < 4; ++fn)
        acc[fm][fn] = __builtin_amdgcn_mfma_f32_16x16x32_bf16(a[fm], b[fn], acc[fm][fn], 0, 0, 0);
  }

  float* ob = out + ((size_t)(b0 + bz) * Tc) * N;
  const float* bias = b2 + (size_t)e * N;
#pragma unroll
  for (int fn = 0; fn < 4; ++fn) {
    int col = n0 + wc * 64 + fn * 16 + (lane & 15);
    float bv = bias[col];
#pragma unroll
    for (int fm = 0; fm < 4; ++fm) {
      int rbase = m0 + wr * 64 + fm * 16 + ((lane >> 4) << 2);
#pragma unroll
      for (int r = 0; r < 4; ++r) {
        ob[(size_t)(rbase + r) * N + col] = acc[fm][fn][r] + bv;
      }
    }
  }
}

extern "C" void kernel_launch(void* const* d_in, const int* in_sizes, int n_in,
                              void* d_out, int out_size, void* d_ws, size_t ws_size,
                              hipStream_t stream) {
  const float* x  = (const float*)d_in[0];
  const float* wg = (const float*)d_in[1];
  const float* W1 = (const float*)d_in[2];
  const float* b1 = (const float*)d_in[3];
  const float* W2 = (const float*)d_in[4];
  const float* b2 = (const float*)d_in[5];
  float* out = (float*)d_out;

  char* ws = (char*)d_ws;
  size_t off = 0;
  float* part = (float*)(ws + off); off += (size_t)Bc * 8 * Cc * 4;   // 1 MB
  float* logits = (float*)(ws + off); off += (size_t)Bc * Ec * 4;
  int* idx = (int*)(ws + off); off += (size_t)Bc * 4;
  off = (off + 255) & ~(size_t)255;
  __hip_bfloat16* w1t = (__hip_bfloat16*)(ws + off); off += (size_t)Ec * HIDc * Cc * 2;  // 10 MB
  __hip_bfloat16* w2t = (__hip_bfloat16*)(ws + off); off += (size_t)Ec * HIDc * Cc * 2;  // 10 MB
  size_t dynoff = (off + 255) & ~(size_t)255;

  const size_t x_per_b = (size_t)Tc * Cc * 2;    // 1 MB
  const size_t h_per_b = (size_t)Tc * HIDc * 2;  // 4 MB
  size_t avail = ws_size > dynoff ? ws_size - dynoff : 0;
  int cb = (int)(avail / (x_per_b + h_per_b));
  if (cb > Bc) cb = Bc;
  if (cb < 1) cb = 1;

  // gating + loss
  k_partial<<<dim3(Bc, 8), 256, 0, stream>>>(x, part);
  k_xg_logits<<<dim3(Bc), 256, 0, stream>>>(part, wg, logits);
  k_gate<<<dim3(1), 256, 0, stream>>>(logits, idx, out + ((size_t)out_size - 1));

  // weights -> bf16, N-major
  k_transpose_cvt<<<dim3(HIDc / 32, Cc / 32, Ec), 256, 0, stream>>>(W1, w1t, Cc, HIDc);
  k_transpose_cvt<<<dim3(Cc / 32, HIDc / 32, Ec), 256, 0, stream>>>(W2, w2t, HIDc, Cc);

  __hip_bfloat16* xbf = (__hip_bfloat16*)(ws + dynoff);
  __hip_bfloat16* hbf = (__hip_bfloat16*)(ws + dynoff + (size_t)cb * x_per_b);

  for (int b0 = 0; b0 < Bc; b0 += cb) {
    int c = (Bc - b0) < cb ? (Bc - b0) : cb;
    int n4 = c * (Tc * Cc / 4);
    k_cvt_x<<<dim3(1024), 256, 0, stream>>>(x + (size_t)b0 * Tc * Cc, (ushort*)xbf, n4);
    k_gemm1<<<dim3(HIDc / 128, Tc / 128, c), 256, 0, stream>>>(xbf, w1t, b1, idx, b0, hbf);
    k_gemm2<<<dim3(Cc / 128, Tc / 128, c), 256, 0, stream>>>(hbf, w2t, b2, idx, b0, out);
  }
}

// Round 2
// 587.127 us; speedup vs baseline: 1.1646x; 1.1646x over previous
//
#include <hip/hip_runtime.h>
#include <hip/hip_bf16.h>
#include <math.h>

typedef __attribute__((ext_vector_type(4))) float f4_t;
typedef __attribute__((ext_vector_type(8))) short s8_t;

// Problem constants
constexpr int Bc = 64;      // batches
constexpr int Tc = 1024;    // tokens per batch (H*W)
constexpr int Cc = 512;     // channels
constexpr int Ec = 5;       // experts
constexpr int HIDc = 2048;  // hidden

// async global->LDS, 16B per lane (linear LDS dest: base + lane*16)
__device__ __forceinline__ void async_copy16(const void* gsrc, void* ldst) {
  __builtin_amdgcn_global_load_lds(
      (const __attribute__((address_space(1))) unsigned int*)gsrc,
      (__attribute__((address_space(3))) unsigned int*)ldst, 16, 0, 0);
}

// ---------------- gating ----------------

// partial sums over token sub-ranges: part[b][p][c] = sum_{t in p-th 128} x[b][t][c]
__global__ void k_partial(const float* __restrict__ x, float* __restrict__ part) {
  int b = blockIdx.x, p = blockIdx.y, tid = threadIdx.x;
  const float* xp = x + ((size_t)b * Tc + (size_t)p * 128) * Cc;
  float s0 = 0.f, s1 = 0.f;
  for (int t = 0; t < 128; ++t) {
    s0 += xp[(size_t)t * Cc + tid];
    s1 += xp[(size_t)t * Cc + tid + 256];
  }
  part[(size_t)(b * 8 + p) * Cc + tid] = s0;
  part[(size_t)(b * 8 + p) * Cc + tid + 256] = s1;
}

// per-batch: finalize xg (mean) in LDS, compute logits[b][e]
__global__ void k_xg_logits(const float* __restrict__ part, const float* __restrict__ wg,
                            float* __restrict__ logits) {
  __shared__ float xg[Cc];
  __shared__ float red[Ec][4];
  int b = blockIdx.x, tid = threadIdx.x;
  for (int c = tid; c < Cc; c += 256) {
    float s = 0.f;
#pragma unroll
    for (int p = 0; p < 8; ++p) s += part[(size_t)(b * 8 + p) * Cc + c];
    xg[c] = s * (1.0f / 1024.0f);
  }
  __syncthreads();
  float le[Ec] = {0.f, 0.f, 0.f, 0.f, 0.f};
  for (int c = tid; c < Cc; c += 256) {
    float v = xg[c];
#pragma unroll
    for (int e = 0; e < Ec; ++e) le[e] += v * wg[c * Ec + e];
  }
#pragma unroll
  for (int e = 0; e < Ec; ++e) {
    float v = le[e];
#pragma unroll
    for (int off = 32; off > 0; off >>= 1) v += __shfl_down(v, off);
    if ((tid & 63) == 0) red[e][tid >> 6] = v;
  }
  __syncthreads();
  if (tid < Ec) {
    float v = red[tid][0] + red[tid][1] + red[tid][2] + red[tid][3];
    v = fminf(fmaxf(v, -50.f), 50.f);
    logits[b * Ec + tid] = v;
  }
}

// argmax per batch, counts, loss
__global__ void k_gate(const float* __restrict__ logits, int* __restrict__ idx,
                       float* __restrict__ loss_out) {
  __shared__ int cnt[Ec];
  int tid = threadIdx.x;
  if (tid < Ec) cnt[tid] = 0;
  __syncthreads();
  if (tid < Bc) {
    const float* lb = logits + tid * Ec;
    int best = 0;
    float bv = lb[0];
#pragma unroll
    for (int e = 1; e < Ec; ++e) {
      float v = lb[e];
      if (v > bv) { bv = v; best = e; }
    }
    idx[tid] = best;
    atomicAdd(&cnt[best], 1);
  }
  __syncthreads();
  if (tid == 0) {
    const float mean = (float)Bc / (float)Ec;  // 12.8
    float var = 0.f;
#pragma unroll
    for (int e = 0; e < Ec; ++e) {
      float d = (float)cnt[e] - mean;
      var += d * d;
    }
    var *= (1.0f / (Ec - 1));
    float loss = 2.f * (var / (mean * mean + 1e-10f));
    loss = fminf(fmaxf(loss, 0.f), 1000.f);
    *loss_out = loss;
  }
}

// ---------------- weight transpose-convert: src (E,K,N) f32 -> dst (E,N,K) bf16 ----------------
__global__ void k_transpose_cvt(const float* __restrict__ src, __hip_bfloat16* __restrict__ dst,
                                int K, int N) {
  __shared__ float tile[32][33];
  int e = blockIdx.z;
  int kb = blockIdx.y * 32, nb = blockIdx.x * 32;
  const float* s = src + (size_t)e * K * N;
  __hip_bfloat16* d = dst + (size_t)e * K * N;
  int lx = threadIdx.x & 31, ly = threadIdx.x >> 5;  // ly: 0..7
#pragma unroll
  for (int r = 0; r < 4; ++r) {
    int k = kb + ly + r * 8;
    tile[ly + r * 8][lx] = s[(size_t)k * N + nb + lx];
  }
  __syncthreads();
#pragma unroll
  for (int r = 0; r < 4; ++r) {
    int n = nb + ly + r * 8;
    d[(size_t)n * K + kb + lx] = __float2bfloat16(tile[lx][ly + r * 8]);
  }
}

// ---------------- x fp32 -> bf16 ----------------
__global__ void k_cvt_x(const float* __restrict__ src, ushort* __restrict__ dst, int n4) {
  int i = blockIdx.x * blockDim.x + threadIdx.x;
  int stride = gridDim.x * blockDim.x;
  const float4* s4 = (const float4*)src;
  ushort4* d4 = (ushort4*)dst;
  for (; i < n4; i += stride) {
    float4 v = s4[i];
    union { __hip_bfloat16 h[4]; ushort4 u; } cv;
    cv.h[0] = __float2bfloat16(v.x);
    cv.h[1] = __float2bfloat16(v.y);
    cv.h[2] = __float2bfloat16(v.z);
    cv.h[3] = __float2bfloat16(v.w);
    d4[i] = cv.u;
  }
}

// ---------------- GEMM1: h = gelu(x @ W1[e] + b1[e]), bf16 out ----------------
// A: xbf [cb][1024][512] (M x K row-major), B: w1t [E][2048][512] (N x K row-major)
__global__ __launch_bounds__(256) void k_gemm1(
    const __hip_bfloat16* __restrict__ xbf, const __hip_bfloat16* __restrict__ w1t,
    const float* __restrict__ b1, const int* __restrict__ idx, int b0,
    __hip_bfloat16* __restrict__ h) {
  constexpr int K = Cc;     // 512
  constexpr int N = HIDc;   // 2048
  __shared__ short As[128 * 32];
  __shared__ short Bs[128 * 32];
  int bz = blockIdx.z;
  int e = idx[b0 + bz];
  int m0 = blockIdx.y * 128;
  int n0 = blockIdx.x * 128;
  const short* Abase = (const short*)(xbf + (size_t)bz * Tc * K) + (size_t)m0 * K;
  const short* Bbase = (const short*)(w1t + (size_t)e * N * K) + (size_t)n0 * K;
  int tid = threadIdx.x;
  int lane = tid & 63, wv = tid >> 6;
  int wr = wv >> 1, wc = wv & 1;
  int c0 = tid, c1 = tid + 256;
  // per-lane global source addresses (LDS dest is linear: base + tid*16B)
  const short* ga0 = Abase + (size_t)(c0 >> 2) * K + ((c0 & 3) << 3);
  const short* ga1 = Abase + (size_t)(c1 >> 2) * K + ((c1 & 3) << 3);
  const short* gb0 = Bbase + (size_t)(c0 >> 2) * K + ((c0 & 3) << 3);
  const short* gb1 = Bbase + (size_t)(c1 >> 2) * K + ((c1 & 3) << 3);

  f4_t acc[4][4] = {};

  for (int k0 = 0; k0 < K; k0 += 32) {
    __syncthreads();
    async_copy16(ga0 + k0, As + c0 * 8);
    async_copy16(ga1 + k0, As + c1 * 8);
    async_copy16(gb0 + k0, Bs + c0 * 8);
    async_copy16(gb1 + k0, Bs + c1 * 8);
    __syncthreads();
    s8_t a[4], b[4];
#pragma unroll
    for (int f = 0; f < 4; ++f)
      a[f] = *(const s8_t*)(As + (wr * 64 + f * 16 + (lane & 15)) * 32 + ((lane >> 4) << 3));
#pragma unroll
    for (int f = 0; f < 4; ++f)
      b[f] = *(const s8_t*)(Bs + (wc * 64 + f * 16 + (lane & 15)) * 32 + ((lane >> 4) << 3));
#pragma unroll
    for (int fm = 0; fm < 4; ++fm)
#pragma unroll
      for (int fn = 0; fn < 4; ++fn)
        acc[fm][fn] = __builtin_amdgcn_mfma_f32_16x16x32_bf16(a[fm], b[fn], acc[fm][fn], 0, 0, 0);
  }

  __hip_bfloat16* hb = h + (size_t)bz * Tc * N;
  const float* bias = b1 + (size_t)e * N;
#pragma unroll
  for (int fn = 0; fn < 4; ++fn) {
    int col = n0 + wc * 64 + fn * 16 + (lane & 15);
    float bv = bias[col];
#pragma unroll
    for (int fm = 0; fm < 4; ++fm) {
      int rbase = m0 + wr * 64 + fm * 16 + ((lane >> 4) << 2);
#pragma unroll
      for (int r = 0; r < 4; ++r) {
        float v = acc[fm][fn][r] + bv;
        v = 0.5f * v * (1.0f + erff(v * 0.70710678118654752f));
        hb[(size_t)(rbase + r) * N + col] = __float2bfloat16(v);
      }
    }
  }
}

// ---------------- GEMM2: y = h @ W2[e] + b2[e], fp32 out ----------------
// A: h [cb][1024][2048] (M x K row-major), B: w2t [E][512][2048] (N x K row-major)
__global__ __launch_bounds__(256) void k_gemm2(
    const __hip_bfloat16* __restrict__ h, const __hip_bfloat16* __restrict__ w2t,
    const float* __restrict__ b2, const int* __restrict__ idx, int b0,
    float* __restrict__ out) {
  constexpr int K = HIDc;  // 2048
  constexpr int N = Cc;    // 512
  __shared__ short As[128 * 32];
  __shared__ short Bs[128 * 32];
  int bz = blockIdx.z;
  int e = idx[b0 + bz];
  int m0 = blockIdx.y * 128;
  int n0 = blockIdx.x * 128;
  const short* Abase = (const short*)(h + (size_t)bz * Tc * K) + (size_t)m0 * K;
  const short* Bbase = (const short*)(w2t + (size_t)e * (size_t)N * K) + (size_t)n0 * K;
  int tid = threadIdx.x;
  int lane = tid & 63, wv = tid >> 6;
  int wr = wv >> 1, wc = wv & 1;
  int c0 = tid, c1 = tid + 256;
  const short* ga0 = Abase + (size_t)(c0 >> 2) * K + ((c0 & 3) << 3);
  const short* ga1 = Abase + (size_t)(c1 >> 2) * K + ((c1 & 3) << 3);
  const short* gb0 = Bbase + (size_t)(c0 >> 2) * K + ((c0 & 3) << 3);
  const short* gb1 = Bbase + (size_t)(c1 >> 2) * K + ((c1 & 3) << 3);

  f4_t acc[4][4] = {};

  for (int k0 = 0; k0 < K; k0 += 32) {
    __syncthreads();
    async_copy16(ga0 + k0, As + c0 * 8);
    async_copy16(ga1 + k0, As + c1 * 8);
    async_copy16(gb0 + k0, Bs + c0 * 8);
    async_copy16(gb1 + k0, Bs + c1 * 8);
    __syncthreads();
    s8_t a[4], b[4];
#pragma unroll
    for (int f = 0; f < 4; ++f)
      a[f] = *(const s8_t*)(As + (wr * 64 + f * 16 + (lane & 15)) * 32 + ((lane >> 4) << 3));
#pragma unroll
    for (int f = 0; f < 4; ++f)
      b[f] = *(const s8_t*)(Bs + (wc * 64 + f * 16 + (lane & 15)) * 32 + ((lane >> 4) << 3));
#pragma unroll
    for (int fm = 0; fm < 4; ++fm)
#pragma unroll
      for (int fn = 0; fn < 4; ++fn)
        acc[fm][fn] = __builtin_amdgcn_mfma_f32_16x16x32_bf16(a[fm], b[fn], acc[fm][fn], 0, 0, 0);
  }

  float* ob = out + ((size_t)(b0 + bz) * Tc) * N;
  const float* bias = b2 + (size_t)e * N;
#pragma unroll
  for (int fn = 0; fn < 4; ++fn) {
    int col = n0 + wc * 64 + fn * 16 + (lane & 15);
    float bv = bias[col];
#pragma unroll
    for (int fm = 0; fm < 4; ++fm) {
      int rbase = m0 + wr * 64 + fm * 16 + ((lane >> 4) << 2);
#pragma unroll
      for (int r = 0; r < 4; ++r) {
        ob[(size_t)(rbase + r) * N + col] = acc[fm][fn][r] + bv;
      }
    }
  }
}

extern "C" void kernel_launch(void* const* d_in, const int* in_sizes, int n_in,
                              void* d_out, int out_size, void* d_ws, size_t ws_size,
                              hipStream_t stream) {
  const float* x  = (const float*)d_in[0];
  const float* wg = (const float*)d_in[1];
  const float* W1 = (const float*)d_in[2];
  const float* b1 = (const float*)d_in[3];
  const float* W2 = (const float*)d_in[4];
  const float* b2 = (const float*)d_in[5];
  float* out = (float*)d_out;

  char* ws = (char*)d_ws;
  size_t off = 0;
  float* part = (float*)(ws + off); off += (size_t)Bc * 8 * Cc * 4;   // 1 MB
  float* logits = (float*)(ws + off); off += (size_t)Bc * Ec * 4;
  int* idx = (int*)(ws + off); off += (size_t)Bc * 4;
  off = (off + 255) & ~(size_t)255;
  __hip_bfloat16* w1t = (__hip_bfloat16*)(ws + off); off += (size_t)Ec * HIDc * Cc * 2;  // 10 MB
  __hip_bfloat16* w2t = (__hip_bfloat16*)(ws + off); off += (size_t)Ec * HIDc * Cc * 2;  // 10 MB
  size_t dynoff = (off + 255) & ~(size_t)255;

  const size_t x_per_b = (size_t)Tc * Cc * 2;    // 1 MB
  const size_t h_per_b = (size_t)Tc * HIDc * 2;  // 4 MB
  size_t avail = ws_size > dynoff ? ws_size - dynoff : 0;
  int cb = (int)(avail / (x_per_b + h_per_b));
  if (cb > Bc) cb = Bc;
  if (cb < 1) cb = 1;

  // gating + loss
  k_partial<<<dim3(Bc, 8), 256, 0, stream>>>(x, part);
  k_xg_logits<<<dim3(Bc), 256, 0, stream>>>(part, wg, logits);
  k_gate<<<dim3(1), 256, 0, stream>>>(logits, idx, out + ((size_t)out_size - 1));

  // weights -> bf16, N-major
  k_transpose_cvt<<<dim3(HIDc / 32, Cc / 32, Ec), 256, 0, stream>>>(W1, w1t, Cc, HIDc);
  k_transpose_cvt<<<dim3(Cc / 32, HIDc / 32, Ec), 256, 0, stream>>>(W2, w2t, HIDc, Cc);

  __hip_bfloat16* xbf = (__hip_bfloat16*)(ws + dynoff);
  __hip_bfloat16* hbf = (__hip_bfloat16*)(ws + dynoff + (size_t)cb * x_per_b);

  for (int b0 = 0; b0 < Bc; b0 += cb) {
    int c = (Bc - b0) < cb ? (Bc - b0) : cb;
    int n4 = c * (Tc * Cc / 4);
    k_cvt_x<<<dim3(1024), 256, 0, stream>>>(x + (size_t)b0 * Tc * Cc, (ushort*)xbf, n4);
    k_gemm1<<<dim3(HIDc / 128, Tc / 128, c), 256, 0, stream>>>(xbf, w1t, b1, idx, b0, hbf);
    k_gemm2<<<dim3(Cc / 128, Tc / 128, c), 256, 0, stream>>>(hbf, w2t, b2, idx, b0, out);
  }
}

// Round 3
// 527.277 us; speedup vs baseline: 1.2968x; 1.1135x over previous
//
#include <hip/hip_runtime.h>
#include <hip/hip_bf16.h>
#include <math.h>

typedef __attribute__((ext_vector_type(4))) float f4_t;
typedef __attribute__((ext_vector_type(8))) short s8_t;

// Problem constants
constexpr int Bc = 64;      // batches
constexpr int Tc = 1024;    // tokens per batch (H*W)
constexpr int Cc = 512;     // channels
constexpr int Ec = 5;       // experts
constexpr int HIDc = 2048;  // hidden

// async global->LDS, 16B per lane (linear LDS dest: wave-uniform base + lane*16)
__device__ __forceinline__ void async_copy16(const void* gsrc, void* ldst) {
  __builtin_amdgcn_global_load_lds(
      (const __attribute__((address_space(1))) unsigned int*)gsrc,
      (__attribute__((address_space(3))) unsigned int*)ldst, 16, 0, 0);
}

// ---------------- gating ----------------

__global__ void k_partial(const float* __restrict__ x, float* __restrict__ part) {
  int b = blockIdx.x, p = blockIdx.y, tid = threadIdx.x;
  const float* xp = x + ((size_t)b * Tc + (size_t)p * 128) * Cc;
  float s0 = 0.f, s1 = 0.f;
  for (int t = 0; t < 128; ++t) {
    s0 += xp[(size_t)t * Cc + tid];
    s1 += xp[(size_t)t * Cc + tid + 256];
  }
  part[(size_t)(b * 8 + p) * Cc + tid] = s0;
  part[(size_t)(b * 8 + p) * Cc + tid + 256] = s1;
}

__global__ void k_xg_logits(const float* __restrict__ part, const float* __restrict__ wg,
                            float* __restrict__ logits) {
  __shared__ float xg[Cc];
  __shared__ float red[Ec][4];
  int b = blockIdx.x, tid = threadIdx.x;
  for (int c = tid; c < Cc; c += 256) {
    float s = 0.f;
#pragma unroll
    for (int p = 0; p < 8; ++p) s += part[(size_t)(b * 8 + p) * Cc + c];
    xg[c] = s * (1.0f / 1024.0f);
  }
  __syncthreads();
  float le[Ec] = {0.f, 0.f, 0.f, 0.f, 0.f};
  for (int c = tid; c < Cc; c += 256) {
    float v = xg[c];
#pragma unroll
    for (int e = 0; e < Ec; ++e) le[e] += v * wg[c * Ec + e];
  }
#pragma unroll
  for (int e = 0; e < Ec; ++e) {
    float v = le[e];
#pragma unroll
    for (int off = 32; off > 0; off >>= 1) v += __shfl_down(v, off);
    if ((tid & 63) == 0) red[e][tid >> 6] = v;
  }
  __syncthreads();
  if (tid < Ec) {
    float v = red[tid][0] + red[tid][1] + red[tid][2] + red[tid][3];
    v = fminf(fmaxf(v, -50.f), 50.f);
    logits[b * Ec + tid] = v;
  }
}

__global__ void k_gate(const float* __restrict__ logits, int* __restrict__ idx,
                       float* __restrict__ loss_out) {
  __shared__ int cnt[Ec];
  int tid = threadIdx.x;
  if (tid < Ec) cnt[tid] = 0;
  __syncthreads();
  if (tid < Bc) {
    const float* lb = logits + tid * Ec;
    int best = 0;
    float bv = lb[0];
#pragma unroll
    for (int e = 1; e < Ec; ++e) {
      float v = lb[e];
      if (v > bv) { bv = v; best = e; }
    }
    idx[tid] = best;
    atomicAdd(&cnt[best], 1);
  }
  __syncthreads();
  if (tid == 0) {
    const float mean = (float)Bc / (float)Ec;  // 12.8
    float var = 0.f;
#pragma unroll
    for (int e = 0; e < Ec; ++e) {
      float d = (float)cnt[e] - mean;
      var += d * d;
    }
    var *= (1.0f / (Ec - 1));
    float loss = 2.f * (var / (mean * mean + 1e-10f));
    loss = fminf(fmaxf(loss, 0.f), 1000.f);
    *loss_out = loss;
  }
}

// ---------------- weight transpose-convert: src (E,K,N) f32 -> dst (E,N,K) bf16 ----------------
__global__ void k_transpose_cvt(const float* __restrict__ src, __hip_bfloat16* __restrict__ dst,
                                int K, int N) {
  __shared__ float tile[32][33];
  int e = blockIdx.z;
  int kb = blockIdx.y * 32, nb = blockIdx.x * 32;
  const float* s = src + (size_t)e * K * N;
  __hip_bfloat16* d = dst + (size_t)e * K * N;
  int lx = threadIdx.x & 31, ly = threadIdx.x >> 5;  // ly: 0..7
#pragma unroll
  for (int r = 0; r < 4; ++r) {
    int k = kb + ly + r * 8;
    tile[ly + r * 8][lx] = s[(size_t)k * N + nb + lx];
  }
  __syncthreads();
#pragma unroll
  for (int r = 0; r < 4; ++r) {
    int n = nb + ly + r * 8;
    d[(size_t)n * K + kb + lx] = __float2bfloat16(tile[lx][ly + r * 8]);
  }
}

// ---------------- x fp32 -> bf16 ----------------
__global__ void k_cvt_x(const float* __restrict__ src, ushort* __restrict__ dst, int n4) {
  int i = blockIdx.x * blockDim.x + threadIdx.x;
  int stride = gridDim.x * blockDim.x;
  const float4* s4 = (const float4*)src;
  ushort4* d4 = (ushort4*)dst;
  for (; i < n4; i += stride) {
    float4 v = s4[i];
    union { __hip_bfloat16 h[4]; ushort4 u; } cv;
    cv.h[0] = __float2bfloat16(v.x);
    cv.h[1] = __float2bfloat16(v.y);
    cv.h[2] = __float2bfloat16(v.z);
    cv.h[3] = __float2bfloat16(v.w);
    d4[i] = cv.u;
  }
}

// =====================================================================
// 256x256 tile, BK=64, 8 waves (2M x 4N), double-buffered LDS, 2-phase
// schedule: STAGE(next) || ds_read+MFMA(cur); one barrier per K-step.
// LDS: 2 bufs x (A 256x64 + B 256x64) bf16 = 128 KiB. 1 block/CU.
// =====================================================================

// GEMM1: h = gelu(x @ W1[e] + b1[e]); A: xbf [cb][1024][512] row-major,
// B: w1t [E][2048][512] N-major. Coalesced h-write via per-wave LDS transpose.
__global__ __launch_bounds__(512, 2) void k_gemm1(
    const __hip_bfloat16* __restrict__ xbf, const __hip_bfloat16* __restrict__ w1t,
    const float* __restrict__ b1, const int* __restrict__ idx, int b0,
    __hip_bfloat16* __restrict__ h) {
  constexpr int K = Cc;     // 512
  constexpr int N = HIDc;   // 2048
  constexpr int NT = K / 64;  // 8
  __shared__ short lds[2][2][256 * 64];

  int bz = blockIdx.z;
  int e = idx[b0 + bz];
  int m0 = blockIdx.y * 256;
  int n0 = blockIdx.x * 256;
  const short* Abase = (const short*)xbf + ((size_t)bz * Tc + m0) * K;
  const short* Bbase = (const short*)w1t + ((size_t)e * N + n0) * K;
  int tid = threadIdx.x;
  int l = tid & 63, w = tid >> 6;
  int wr = w >> 2, wc = w & 3;  // wave tile: rows wr*128, cols wc*64

  // staging: per thread 4 x 16B per matrix per K-step.
  // load i covers LDS bytes tid*16 + i*8192  == row (i*64 + tid>>3), col-shorts (tid&7)*8
  int s_row = tid >> 3;
  int s_col = (tid & 7) * 8;
  const short* gA[4];
  const short* gB[4];
#pragma unroll
  for (int i = 0; i < 4; ++i) {
    gA[i] = Abase + (size_t)(i * 64 + s_row) * K + s_col;
    gB[i] = Bbase + (size_t)(i * 64 + s_row) * K + s_col;
  }

  // ds_read fragment offsets (shorts)
  int a_off = (wr * 128 + (l & 15)) * 64 + (l >> 4) * 8;
  int b_off = (wc * 64 + (l & 15)) * 64 + (l >> 4) * 8;

  f4_t acc[8][4] = {};

  // prologue: stage K-step 0 into buf 0
#pragma unroll
  for (int i = 0; i < 4; ++i) {
    async_copy16(gA[i], (char*)&lds[0][0][0] + tid * 16 + i * 8192);
    async_copy16(gB[i], (char*)&lds[0][1][0] + tid * 16 + i * 8192);
  }
  __syncthreads();  // drains vmcnt

  for (int t = 0; t < NT; ++t) {
    int cur = t & 1;
    const short* As = &lds[cur][0][0];
    const short* Bs = &lds[cur][1][0];
    if (t + 1 < NT) {
      int k0 = (t + 1) * 64;
#pragma unroll
      for (int i = 0; i < 4; ++i) {
        async_copy16(gA[i] + k0, (char*)&lds[cur ^ 1][0][0] + tid * 16 + i * 8192);
        async_copy16(gB[i] + k0, (char*)&lds[cur ^ 1][1][0] + tid * 16 + i * 8192);
      }
    }
#pragma unroll
    for (int kk = 0; kk < 2; ++kk) {
      s8_t a[8], b[4];
#pragma unroll
      for (int f = 0; f < 8; ++f)
        a[f] = *(const s8_t*)(As + a_off + f * 16 * 64 + kk * 32);
#pragma unroll
      for (int f = 0; f < 4; ++f)
        b[f] = *(const s8_t*)(Bs + b_off + f * 16 * 64 + kk * 32);
#pragma unroll
      for (int fm = 0; fm < 8; ++fm)
#pragma unroll
        for (int fn = 0; fn < 4; ++fn)
          acc[fm][fn] = __builtin_amdgcn_mfma_f32_16x16x32_bf16(a[fm], b[fn], acc[fm][fn], 0, 0, 0);
    }
    if (t + 1 < NT) __syncthreads();
  }

  // epilogue: bias + gelu, per-wave LDS transpose -> coalesced 16B row stores
  __syncthreads();  // all waves done reading LDS bufs
  __hip_bfloat16* chunk = (__hip_bfloat16*)&lds[0][0][0] + w * 8192;  // 16KB per wave
  const float* bias = b1 + (size_t)e * N;
#pragma unroll
  for (int fn = 0; fn < 4; ++fn) {
    int col = n0 + wc * 64 + fn * 16 + (l & 15);
    float bv = bias[col];
#pragma unroll
    for (int fm = 0; fm < 8; ++fm) {
      int row = fm * 16 + ((l >> 4) << 2);
#pragma unroll
      for (int j = 0; j < 4; ++j) {
        float v = acc[fm][fn][j] + bv;
        v = 0.5f * v * (1.0f + erff(v * 0.70710678118654752f));
        chunk[(row + j) * 64 + fn * 16 + (l & 15)] = __float2bfloat16(v);
      }
    }
  }
  // no barrier needed: each wave reads only its own chunk (same-wave lgkm dep)
  short* hb = (short*)(h + (size_t)bz * Tc * N);
  int colb = n0 + wc * 64 + (l & 7) * 8;
#pragma unroll
  for (int p = 0; p < 16; ++p) {
    int row = p * 8 + (l >> 3);
    s8_t vrow = *(const s8_t*)((const short*)chunk + row * 64 + (l & 7) * 8);
    *(s8_t*)(hb + (size_t)(m0 + wr * 128 + row) * N + colb) = vrow;
  }
}

// GEMM2: y = h @ W2[e] + b2[e]; A: h [cb][1024][2048] row-major,
// B: w2t [E][512][2048] N-major. f32 out (64B-coalesced direct stores).
__global__ __launch_bounds__(512, 2) void k_gemm2(
    const __hip_bfloat16* __restrict__ h, const __hip_bfloat16* __restrict__ w2t,
    const float* __restrict__ b2, const int* __restrict__ idx, int b0,
    float* __restrict__ out) {
  constexpr int K = HIDc;  // 2048
  constexpr int N = Cc;    // 512
  constexpr int NT = K / 64;  // 32
  __shared__ short lds[2][2][256 * 64];

  int bz = blockIdx.z;
  int e = idx[b0 + bz];
  int m0 = blockIdx.y * 256;
  int n0 = blockIdx.x * 256;
  const short* Abase = (const short*)h + ((size_t)bz * Tc + m0) * K;
  const short* Bbase = (const short*)w2t + ((size_t)e * N + n0) * K;
  int tid = threadIdx.x;
  int l = tid & 63, w = tid >> 6;
  int wr = w >> 2, wc = w & 3;

  int s_row = tid >> 3;
  int s_col = (tid & 7) * 8;
  const short* gA[4];
  const short* gB[4];
#pragma unroll
  for (int i = 0; i < 4; ++i) {
    gA[i] = Abase + (size_t)(i * 64 + s_row) * K + s_col;
    gB[i] = Bbase + (size_t)(i * 64 + s_row) * K + s_col;
  }

  int a_off = (wr * 128 + (l & 15)) * 64 + (l >> 4) * 8;
  int b_off = (wc * 64 + (l & 15)) * 64 + (l >> 4) * 8;

  f4_t acc[8][4] = {};

#pragma unroll
  for (int i = 0; i < 4; ++i) {
    async_copy16(gA[i], (char*)&lds[0][0][0] + tid * 16 + i * 8192);
    async_copy16(gB[i], (char*)&lds[0][1][0] + tid * 16 + i * 8192);
  }
  __syncthreads();

  for (int t = 0; t < NT; ++t) {
    int cur = t & 1;
    const short* As = &lds[cur][0][0];
    const short* Bs = &lds[cur][1][0];
    if (t + 1 < NT) {
      int k0 = (t + 1) * 64;
#pragma unroll
      for (int i = 0; i < 4; ++i) {
        async_copy16(gA[i] + k0, (char*)&lds[cur ^ 1][0][0] + tid * 16 + i * 8192);
        async_copy16(gB[i] + k0, (char*)&lds[cur ^ 1][1][0] + tid * 16 + i * 8192);
      }
    }
#pragma unroll
    for (int kk = 0; kk < 2; ++kk) {
      s8_t a[8], b[4];
#pragma unroll
      for (int f = 0; f < 8; ++f)
        a[f] = *(const s8_t*)(As + a_off + f * 16 * 64 + kk * 32);
#pragma unroll
      for (int f = 0; f < 4; ++f)
        b[f] = *(const s8_t*)(Bs + b_off + f * 16 * 64 + kk * 32);
#pragma unroll
      for (int fm = 0; fm < 8; ++fm)
#pragma unroll
        for (int fn = 0; fn < 4; ++fn)
          acc[fm][fn] = __builtin_amdgcn_mfma_f32_16x16x32_bf16(a[fm], b[fn], acc[fm][fn], 0, 0, 0);
    }
    if (t + 1 < NT) __syncthreads();
  }

  float* ob = out + (size_t)(b0 + bz) * Tc * N;
  const float* bias = b2 + (size_t)e * N;
#pragma unroll
  for (int fn = 0; fn < 4; ++fn) {
    int col = n0 + wc * 64 + fn * 16 + (l & 15);
    float bv = bias[col];
#pragma unroll
    for (int fm = 0; fm < 8; ++fm) {
      int rbase = m0 + wr * 128 + fm * 16 + ((l >> 4) << 2);
#pragma unroll
      for (int j = 0; j < 4; ++j) {
        ob[(size_t)(rbase + j) * N + col] = acc[fm][fn][j] + bv;
      }
    }
  }
}

extern "C" void kernel_launch(void* const* d_in, const int* in_sizes, int n_in,
                              void* d_out, int out_size, void* d_ws, size_t ws_size,
                              hipStream_t stream) {
  const float* x  = (const float*)d_in[0];
  const float* wg = (const float*)d_in[1];
  const float* W1 = (const float*)d_in[2];
  const float* b1 = (const float*)d_in[3];
  const float* W2 = (const float*)d_in[4];
  const float* b2 = (const float*)d_in[5];
  float* out = (float*)d_out;

  char* ws = (char*)d_ws;
  size_t off = 0;
  float* part = (float*)(ws + off); off += (size_t)Bc * 8 * Cc * 4;   // 1 MB
  float* logits = (float*)(ws + off); off += (size_t)Bc * Ec * 4;
  int* idx = (int*)(ws + off); off += (size_t)Bc * 4;
  off = (off + 255) & ~(size_t)255;
  __hip_bfloat16* w1t = (__hip_bfloat16*)(ws + off); off += (size_t)Ec * HIDc * Cc * 2;  // 10 MB
  __hip_bfloat16* w2t = (__hip_bfloat16*)(ws + off); off += (size_t)Ec * HIDc * Cc * 2;  // 10 MB
  size_t dynoff = (off + 255) & ~(size_t)255;

  const size_t x_per_b = (size_t)Tc * Cc * 2;    // 1 MB
  const size_t h_per_b = (size_t)Tc * HIDc * 2;  // 4 MB
  size_t avail = ws_size > dynoff ? ws_size - dynoff : 0;
  int cb = (int)(avail / (x_per_b + h_per_b));
  if (cb > Bc) cb = Bc;
  if (cb < 1) cb = 1;

  // gating + loss
  k_partial<<<dim3(Bc, 8), 256, 0, stream>>>(x, part);
  k_xg_logits<<<dim3(Bc), 256, 0, stream>>>(part, wg, logits);
  k_gate<<<dim3(1), 256, 0, stream>>>(logits, idx, out + ((size_t)out_size - 1));

  // weights -> bf16, N-major
  k_transpose_cvt<<<dim3(HIDc / 32, Cc / 32, Ec), 256, 0, stream>>>(W1, w1t, Cc, HIDc);
  k_transpose_cvt<<<dim3(Cc / 32, HIDc / 32, Ec), 256, 0, stream>>>(W2, w2t, HIDc, Cc);

  __hip_bfloat16* xbf = (__hip_bfloat16*)(ws + dynoff);
  __hip_bfloat16* hbf = (__hip_bfloat16*)(ws + dynoff + (size_t)cb * x_per_b);

  for (int b0 = 0; b0 < Bc; b0 += cb) {
    int c = (Bc - b0) < cb ? (Bc - b0) : cb;
    int n4 = c * (Tc * Cc / 4);
    k_cvt_x<<<dim3(1024), 256, 0, stream>>>(x + (size_t)b0 * Tc * Cc, (ushort*)xbf, n4);
    k_gemm1<<<dim3(HIDc / 256, Tc / 256, c), 512, 0, stream>>>(xbf, w1t, b1, idx, b0, hbf);
    k_gemm2<<<dim3(Cc / 256, Tc / 256, c), 512, 0, stream>>>(hbf, w2t, b2, idx, b0, out);
  }
}

// Round 4
// 495.133 us; speedup vs baseline: 1.3810x; 1.0649x over previous
//
#include <hip/hip_runtime.h>
#include <hip/hip_bf16.h>
#include <math.h>

typedef __attribute__((ext_vector_type(4))) float f4_t;
typedef __attribute__((ext_vector_type(8))) short s8_t;

constexpr int Bc = 64;      // batches
constexpr int Tc = 1024;    // tokens per batch (H*W)
constexpr int Cc = 512;     // channels
constexpr int Ec = 5;       // experts
constexpr int HIDc = 2048;  // hidden

// async global->LDS, 16B per lane (linear LDS dest: wave-uniform base + lane*16)
__device__ __forceinline__ void async_copy16(const void* gsrc, void* ldst) {
  __builtin_amdgcn_global_load_lds(
      (const __attribute__((address_space(1))) unsigned int*)gsrc,
      (__attribute__((address_space(3))) unsigned int*)ldst, 16, 0, 0);
}

// exact-grade gelu: A&S 7.1.26 erf (|eps|<=1.5e-7), branchless, no libm erff
__device__ __forceinline__ float gelu_f(float v) {
  float u = v * 0.70710678118654752f;
  float ax = fabsf(u);
  float t = __frcp_rn(1.0f + 0.3275911f * ax);
  float p = t * (0.254829592f +
           t * (-0.284496736f +
           t * (1.421413741f +
           t * (-1.453152027f +
           t * 1.061405429f))));
  float er = 1.0f - p * __expf(-u * u);
  er = copysignf(er, u);
  return 0.5f * v * (1.0f + er);
}

// ---------------- gating / prep ----------------

// fused: x -> bf16 AND partial column sums (one pass over x)
__global__ void k_prep(const float* __restrict__ x, ushort* __restrict__ xbf,
                       float* __restrict__ part) {
  int b = blockIdx.x, p = blockIdx.y, tid = threadIdx.x;
  const float4* xp = (const float4*)(x + ((size_t)b * Tc + (size_t)p * 128) * Cc);
  ushort4* op = (ushort4*)(xbf + ((size_t)b * Tc + (size_t)p * 128) * Cc);
  int c4 = tid & 127, r0 = tid >> 7;
  float4 s = {0.f, 0.f, 0.f, 0.f};
  for (int r = r0; r < 128; r += 2) {
    float4 v = xp[(size_t)r * 128 + c4];
    s.x += v.x; s.y += v.y; s.z += v.z; s.w += v.w;
    union { __hip_bfloat16 h[4]; ushort4 u; } cv;
    cv.h[0] = __float2bfloat16(v.x);
    cv.h[1] = __float2bfloat16(v.y);
    cv.h[2] = __float2bfloat16(v.z);
    cv.h[3] = __float2bfloat16(v.w);
    op[(size_t)r * 128 + c4] = cv.u;
  }
  __shared__ float4 sh[128];
  if (r0) sh[c4] = s;
  __syncthreads();
  if (!r0) {
    float4 o = sh[c4];
    s.x += o.x; s.y += o.y; s.z += o.z; s.w += o.w;
    ((float4*)part)[(size_t)(b * 8 + p) * 128 + c4] = s;
  }
}

// fallback pair (used only when ws too small for full xbf)
__global__ void k_partial(const float* __restrict__ x, float* __restrict__ part) {
  int b = blockIdx.x, p = blockIdx.y, tid = threadIdx.x;
  const float* xp = x + ((size_t)b * Tc + (size_t)p * 128) * Cc;
  float s0 = 0.f, s1 = 0.f;
  for (int t = 0; t < 128; ++t) {
    s0 += xp[(size_t)t * Cc + tid];
    s1 += xp[(size_t)t * Cc + tid + 256];
  }
  part[(size_t)(b * 8 + p) * Cc + tid] = s0;
  part[(size_t)(b * 8 + p) * Cc + tid + 256] = s1;
}

__global__ void k_cvt_x(const float* __restrict__ src, ushort* __restrict__ dst, int n4) {
  int i = blockIdx.x * blockDim.x + threadIdx.x;
  int stride = gridDim.x * blockDim.x;
  const float4* s4 = (const float4*)src;
  ushort4* d4 = (ushort4*)dst;
  for (; i < n4; i += stride) {
    float4 v = s4[i];
    union { __hip_bfloat16 h[4]; ushort4 u; } cv;
    cv.h[0] = __float2bfloat16(v.x);
    cv.h[1] = __float2bfloat16(v.y);
    cv.h[2] = __float2bfloat16(v.z);
    cv.h[3] = __float2bfloat16(v.w);
    d4[i] = cv.u;
  }
}

__global__ void k_xg_logits(const float* __restrict__ part, const float* __restrict__ wg,
                            float* __restrict__ logits) {
  __shared__ float xg[Cc];
  __shared__ float red[Ec][4];
  int b = blockIdx.x, tid = threadIdx.x;
  for (int c = tid; c < Cc; c += 256) {
    float s = 0.f;
#pragma unroll
    for (int p = 0; p < 8; ++p) s += part[(size_t)(b * 8 + p) * Cc + c];
    xg[c] = s * (1.0f / 1024.0f);
  }
  __syncthreads();
  float le[Ec] = {0.f, 0.f, 0.f, 0.f, 0.f};
  for (int c = tid; c < Cc; c += 256) {
    float v = xg[c];
#pragma unroll
    for (int e = 0; e < Ec; ++e) le[e] += v * wg[c * Ec + e];
  }
#pragma unroll
  for (int e = 0; e < Ec; ++e) {
    float v = le[e];
#pragma unroll
    for (int off = 32; off > 0; off >>= 1) v += __shfl_down(v, off);
    if ((tid & 63) == 0) red[e][tid >> 6] = v;
  }
  __syncthreads();
  if (tid < Ec) {
    float v = red[tid][0] + red[tid][1] + red[tid][2] + red[tid][3];
    v = fminf(fmaxf(v, -50.f), 50.f);
    logits[b * Ec + tid] = v;
  }
}

__global__ void k_gate(const float* __restrict__ logits, int* __restrict__ idx,
                       float* __restrict__ loss_out) {
  __shared__ int cnt[Ec];
  int tid = threadIdx.x;
  if (tid < Ec) cnt[tid] = 0;
  __syncthreads();
  if (tid < Bc) {
    const float* lb = logits + tid * Ec;
    int best = 0;
    float bv = lb[0];
#pragma unroll
    for (int e = 1; e < Ec; ++e) {
      float v = lb[e];
      if (v > bv) { bv = v; best = e; }
    }
    idx[tid] = best;
    atomicAdd(&cnt[best], 1);
  }
  __syncthreads();
  if (tid == 0) {
    const float mean = (float)Bc / (float)Ec;
    float var = 0.f;
#pragma unroll
    for (int e = 0; e < Ec; ++e) {
      float d = (float)cnt[e] - mean;
      var += d * d;
    }
    var *= (1.0f / (Ec - 1));
    float loss = 2.f * (var / (mean * mean + 1e-10f));
    loss = fminf(fmaxf(loss, 0.f), 1000.f);
    *loss_out = loss;
  }
}

// ---------------- weight transpose-convert: (E,K,N) f32 -> (E,N,K) bf16 ----------------
__global__ void k_transpose_cvt(const float* __restrict__ src, __hip_bfloat16* __restrict__ dst,
                                int K, int N) {
  __shared__ float tile[32][33];
  int e = blockIdx.z;
  int kb = blockIdx.y * 32, nb = blockIdx.x * 32;
  const float* s = src + (size_t)e * K * N;
  __hip_bfloat16* d = dst + (size_t)e * K * N;
  int lx = threadIdx.x & 31, ly = threadIdx.x >> 5;
#pragma unroll
  for (int r = 0; r < 4; ++r) {
    int k = kb + ly + r * 8;
    tile[ly + r * 8][lx] = s[(size_t)k * N + nb + lx];
  }
  __syncthreads();
#pragma unroll
  for (int r = 0; r < 4; ++r) {
    int n = nb + ly + r * 8;
    d[(size_t)n * K + kb + lx] = __float2bfloat16(tile[lx][ly + r * 8]);
  }
}

// =====================================================================
// Swizzle scheme (rule 21, both-sides involution): LDS tile [R][64] bf16,
// 16B slots: 8/row.  phys_slot = logical_slot ^ (row&7).  global_load_lds
// dest stays LINEAR; the global SOURCE col-group is pre-permuted; ds_read
// applies the same XOR.  16-way bank conflict -> 2-way (free).
// =====================================================================

// GEMM1: h = gelu(x @ W1[e] + b1[e]).  128x128 tile, BK=64, 4 waves,
// LDS 64KB -> 2 blocks/CU (epilogue/drain overlap across blocks).
__global__ __launch_bounds__(256, 2) void k_gemm1(
    const __hip_bfloat16* __restrict__ xbf, const __hip_bfloat16* __restrict__ w1t,
    const float* __restrict__ b1, const int* __restrict__ idx, int b0, int nz,
    __hip_bfloat16* __restrict__ h) {
  constexpr int K = Cc;     // 512
  constexpr int N = HIDc;   // 2048
  constexpr int NT = K / 64;  // 8
  constexpr int NBX = N / 128, NBY = Tc / 128;  // 16, 8
  __shared__ short lds[2][2][128 * 64];  // 64 KB

  // T1: XCD-aware bijective chunked swizzle (nwg = 128*nz, %8==0)
  int nwg = NBX * NBY * nz;
  int cpx = nwg >> 3;
  int lg = (blockIdx.x & 7) * cpx + (blockIdx.x >> 3);
  int bx = lg % NBX, by = (lg / NBX) % NBY, bz = lg / (NBX * NBY);

  int e = idx[b0 + bz];
  int m0 = by * 128, n0 = bx * 128;
  const short* Ab = (const short*)xbf + ((size_t)bz * Tc + m0) * K;
  const short* Bb = (const short*)w1t + ((size_t)e * N + n0) * K;
  int tid = threadIdx.x, l = tid & 63, w = tid >> 6;
  int wr = w >> 1, wc = w & 1;

  // staging: 4 loads/thread/matrix, source pre-swizzled
  const short* gA[4];
  const short* gB[4];
  int loff[4];
#pragma unroll
  for (int i = 0; i < 4; ++i) {
    int sp = i * 256 + tid;
    int r = sp >> 3;
    int c8 = ((sp & 7) ^ (r & 7)) << 3;
    gA[i] = Ab + (size_t)r * K + c8;
    gB[i] = Bb + (size_t)r * K + c8;
    loff[i] = sp * 16;
  }

  // frag read offsets: byte = row*128 + ((kk*4 + l>>4) ^ (l&7))*16
  int arow = wr * 64 + (l & 15);
  int brow = wc * 64 + (l & 15);
  int s0 = (((l >> 4)) ^ (l & 7)) << 4;
  int s1 = (((l >> 4) + 4) ^ (l & 7)) << 4;

  f4_t acc[4][4] = {};

#pragma unroll
  for (int i = 0; i < 4; ++i) {
    async_copy16(gA[i], (char*)&lds[0][0][0] + loff[i]);
    async_copy16(gB[i], (char*)&lds[0][1][0] + loff[i]);
  }
  __syncthreads();

  for (int t = 0; t < NT; ++t) {
    int cur = t & 1;
    if (t + 1 < NT) {
      int k0 = (t + 1) * 64;
#pragma unroll
      for (int i = 0; i < 4; ++i) {
        async_copy16(gA[i] + k0, (char*)&lds[cur ^ 1][0][0] + loff[i]);
        async_copy16(gB[i] + k0, (char*)&lds[cur ^ 1][1][0] + loff[i]);
      }
    }
    const char* As = (const char*)&lds[cur][0][0];
    const char* Bs = (const char*)&lds[cur][1][0];
#pragma unroll
    for (int kk = 0; kk < 2; ++kk) {
      int sk = kk ? s1 : s0;
      s8_t a[4], b[4];
#pragma unroll
      for (int f = 0; f < 4; ++f) a[f] = *(const s8_t*)(As + (arow + f * 16) * 128 + sk);
#pragma unroll
      for (int f = 0; f < 4; ++f) b[f] = *(const s8_t*)(Bs + (brow + f * 16) * 128 + sk);
#pragma unroll
      for (int fm = 0; fm < 4; ++fm)
#pragma unroll
        for (int fn = 0; fn < 4; ++fn)
          acc[fm][fn] = __builtin_amdgcn_mfma_f32_16x16x32_bf16(a[fm], b[fn], acc[fm][fn], 0, 0, 0);
    }
    __syncthreads();
  }

  // epilogue: bias+gelu -> per-wave LDS transpose (stride 80: 16B-aligned,
  // row affects banks) -> coalesced 16B row stores
  short* chunk = &lds[0][0][0] + w * (64 * 80);
  const float* bias = b1 + (size_t)e * N;
#pragma unroll
  for (int fn = 0; fn < 4; ++fn) {
    float bv = bias[n0 + wc * 64 + fn * 16 + (l & 15)];
#pragma unroll
    for (int fm = 0; fm < 4; ++fm) {
      int r4 = fm * 16 + ((l >> 4) << 2);
#pragma unroll
      for (int j = 0; j < 4; ++j) {
        float v = gelu_f(acc[fm][fn][j] + bv);
        chunk[(r4 + j) * 80 + fn * 16 + (l & 15)] =
            (short)__bfloat16_as_ushort(__float2bfloat16(v));
      }
    }
  }
  short* hb = (short*)(h + (size_t)bz * Tc * N);
  int cc = (l & 7) * 8;
#pragma unroll
  for (int p = 0; p < 8; ++p) {
    int rr = p * 8 + (l >> 3);
    s8_t v = *(const s8_t*)(chunk + rr * 80 + cc);
    *(s8_t*)(hb + (size_t)(m0 + wr * 64 + rr) * N + n0 + wc * 64 + cc) = v;
  }
}

// GEMM2: y = h @ W2[e] + b2[e].  256x256 tile, BK=64, 8 waves, swizzled.
__global__ __launch_bounds__(512, 2) void k_gemm2(
    const __hip_bfloat16* __restrict__ h, const __hip_bfloat16* __restrict__ w2t,
    const float* __restrict__ b2, const int* __restrict__ idx, int b0, int nz,
    float* __restrict__ out) {
  constexpr int K = HIDc;  // 2048
  constexpr int N = Cc;    // 512
  constexpr int NT = K / 64;  // 32
  constexpr int NBX = N / 256, NBY = Tc / 256;  // 2, 4
  __shared__ short lds[2][2][256 * 64];  // 128 KB

  int nwg = NBX * NBY * nz;  // 8*nz, %8==0
  int cpx = nwg >> 3;
  int lg = (blockIdx.x & 7) * cpx + (blockIdx.x >> 3);
  int bx = lg % NBX, by = (lg / NBX) % NBY, bz = lg / (NBX * NBY);

  int e = idx[b0 + bz];
  int m0 = by * 256, n0 = bx * 256;
  const short* Ab = (const short*)h + ((size_t)bz * Tc + m0) * K;
  const short* Bb = (const short*)w2t + ((size_t)e * N + n0) * K;
  int tid = threadIdx.x, l = tid & 63, w = tid >> 6;
  int wr = w >> 2, wc = w & 3;

  const short* gA[4];
  const short* gB[4];
  int loff[4];
#pragma unroll
  for (int i = 0; i < 4; ++i) {
    int sp = i * 512 + tid;
    int r = sp >> 3;
    int c8 = ((sp & 7) ^ (r & 7)) << 3;
    gA[i] = Ab + (size_t)r * K + c8;
    gB[i] = Bb + (size_t)r * K + c8;
    loff[i] = sp * 16;
  }

  int arow = wr * 128 + (l & 15);
  int brow = wc * 64 + (l & 15);
  int s0 = (((l >> 4)) ^ (l & 7)) << 4;
  int s1 = (((l >> 4) + 4) ^ (l & 7)) << 4;

  f4_t acc[8][4] = {};

#pragma unroll
  for (int i = 0; i < 4; ++i) {
    async_copy16(gA[i], (char*)&lds[0][0][0] + loff[i]);
    async_copy16(gB[i], (char*)&lds[0][1][0] + loff[i]);
  }
  __syncthreads();

  for (int t = 0; t < NT; ++t) {
    int cur = t & 1;
    if (t + 1 < NT) {
      int k0 = (t + 1) * 64;
#pragma unroll
      for (int i = 0; i < 4; ++i) {
        async_copy16(gA[i] + k0, (char*)&lds[cur ^ 1][0][0] + loff[i]);
        async_copy16(gB[i] + k0, (char*)&lds[cur ^ 1][1][0] + loff[i]);
      }
    }
    const char* As = (const char*)&lds[cur][0][0];
    const char* Bs = (const char*)&lds[cur][1][0];
#pragma unroll
    for (int kk = 0; kk < 2; ++kk) {
      int sk = kk ? s1 : s0;
      s8_t a[8], b[4];
#pragma unroll
      for (int f = 0; f < 8; ++f) a[f] = *(const s8_t*)(As + (arow + f * 16) * 128 + sk);
#pragma unroll
      for (int f = 0; f < 4; ++f) b[f] = *(const s8_t*)(Bs + (brow + f * 16) * 128 + sk);
#pragma unroll
      for (int fm = 0; fm < 8; ++fm)
#pragma unroll
        for (int fn = 0; fn < 4; ++fn)
          acc[fm][fn] = __builtin_amdgcn_mfma_f32_16x16x32_bf16(a[fm], b[fn], acc[fm][fn], 0, 0, 0);
    }
    __syncthreads();
  }

  float* ob = out + (size_t)(b0 + bz) * Tc * N;
  const float* bias = b2 + (size_t)e * N;
#pragma unroll
  for (int fn = 0; fn < 4; ++fn) {
    int col = n0 + wc * 64 + fn * 16 + (l & 15);
    float bv = bias[col];
#pragma unroll
    for (int fm = 0; fm < 8; ++fm) {
      int rbase = m0 + wr * 128 + fm * 16 + ((l >> 4) << 2);
#pragma unroll
      for (int j = 0; j < 4; ++j) {
        ob[(size_t)(rbase + j) * N + col] = acc[fm][fn][j] + bv;
      }
    }
  }
}

extern "C" void kernel_launch(void* const* d_in, const int* in_sizes, int n_in,
                              void* d_out, int out_size, void* d_ws, size_t ws_size,
                              hipStream_t stream) {
  const float* x  = (const float*)d_in[0];
  const float* wg = (const float*)d_in[1];
  const float* W1 = (const float*)d_in[2];
  const float* b1 = (const float*)d_in[3];
  const float* W2 = (const float*)d_in[4];
  const float* b2 = (const float*)d_in[5];
  float* out = (float*)d_out;

  char* ws = (char*)d_ws;
  size_t off = 0;
  float* part = (float*)(ws + off); off += (size_t)Bc * 8 * Cc * 4;
  float* logits = (float*)(ws + off); off += (size_t)Bc * Ec * 4;
  int* idx = (int*)(ws + off); off += (size_t)Bc * 4;
  off = (off + 255) & ~(size_t)255;
  __hip_bfloat16* w1t = (__hip_bfloat16*)(ws + off); off += (size_t)Ec * HIDc * Cc * 2;
  __hip_bfloat16* w2t = (__hip_bfloat16*)(ws + off); off += (size_t)Ec * HIDc * Cc * 2;
  size_t dynoff = (off + 255) & ~(size_t)255;

  const size_t x_all = (size_t)Bc * Tc * Cc * 2;   // 64 MB
  const size_t x_per_b = (size_t)Tc * Cc * 2;      // 1 MB
  const size_t h_per_b = (size_t)Tc * HIDc * 2;    // 4 MB

  // weights -> bf16, N-major
  k_transpose_cvt<<<dim3(HIDc / 32, Cc / 32, Ec), 256, 0, stream>>>(W1, w1t, Cc, HIDc);
  k_transpose_cvt<<<dim3(Cc / 32, HIDc / 32, Ec), 256, 0, stream>>>(W2, w2t, HIDc, Cc);

  if (ws_size >= dynoff + x_all + h_per_b) {
    // fused path: full xbf, one pass over x computes bf16 + partial sums
    __hip_bfloat16* xbf = (__hip_bfloat16*)(ws + dynoff);
    __hip_bfloat16* hbf = (__hip_bfloat16*)(ws + dynoff + x_all);
    int cb = (int)((ws_size - dynoff - x_all) / h_per_b);
    if (cb > Bc) cb = Bc;

    k_prep<<<dim3(Bc, 8), 256, 0, stream>>>(x, (ushort*)xbf, part);
    k_xg_logits<<<dim3(Bc), 256, 0, stream>>>(part, wg, logits);
    k_gate<<<dim3(1), 256, 0, stream>>>(logits, idx, out + ((size_t)out_size - 1));

    for (int b0 = 0; b0 < Bc; b0 += cb) {
      int c = (Bc - b0) < cb ? (Bc - b0) : cb;
      const __hip_bfloat16* xc = xbf + (size_t)b0 * Tc * Cc;
      k_gemm1<<<dim3((HIDc / 128) * (Tc / 128) * c), 256, 0, stream>>>(
          xc, w1t, b1, idx, b0, c, hbf);
      k_gemm2<<<dim3((Cc / 256) * (Tc / 256) * c), 512, 0, stream>>>(
          hbf, w2t, b2, idx, b0, c, out);
    }
  } else {
    // fallback: chunked x conversion
    size_t avail = ws_size > dynoff ? ws_size - dynoff : 0;
    int cb = (int)(avail / (x_per_b + h_per_b));
    if (cb > Bc) cb = Bc;
    if (cb < 1) cb = 1;
    __hip_bfloat16* xbf = (__hip_bfloat16*)(ws + dynoff);
    __hip_bfloat16* hbf = (__hip_bfloat16*)(ws + dynoff + (size_t)cb * x_per_b);

    k_partial<<<dim3(Bc, 8), 256, 0, stream>>>(x, part);
    k_xg_logits<<<dim3(Bc), 256, 0, stream>>>(part, wg, logits);
    k_gate<<<dim3(1), 256, 0, stream>>>(logits, idx, out + ((size_t)out_size - 1));

    for (int b0 = 0; b0 < Bc; b0 += cb) {
      int c = (Bc - b0) < cb ? (Bc - b0) : cb;
      int n4 = c * (Tc * Cc / 4);
      k_cvt_x<<<dim3(1024), 256, 0, stream>>>(x + (size_t)b0 * Tc * Cc, (ushort*)xbf, n4);
      k_gemm1<<<dim3((HIDc / 128) * (Tc / 128) * c), 256, 0, stream>>>(
          xbf, w1t, b1, idx, 0 + b0, c, hbf);
      k_gemm2<<<dim3((Cc / 256) * (Tc / 256) * c), 512, 0, stream>>>(
          hbf, w2t, b2, idx, b0, c, out);
    }
  }
}

// Round 5
// 484.445 us; speedup vs baseline: 1.4115x; 1.0221x over previous
//
#include <hip/hip_runtime.h>
#include <hip/hip_bf16.h>
#include <math.h>

typedef __attribute__((ext_vector_type(4))) float f4_t;
typedef __attribute__((ext_vector_type(8))) short s8_t;

constexpr int Bc = 64;      // batches
constexpr int Tc = 1024;    // tokens per batch (H*W)
constexpr int Cc = 512;     // channels
constexpr int Ec = 5;       // experts
constexpr int HIDc = 2048;  // hidden

// async global->LDS, 16B per lane (linear LDS dest: wave-uniform base + lane*16)
__device__ __forceinline__ void async_copy16(const void* gsrc, void* ldst) {
  __builtin_amdgcn_global_load_lds(
      (const __attribute__((address_space(1))) unsigned int*)gsrc,
      (__attribute__((address_space(3))) unsigned int*)ldst, 16, 0, 0);
}

// exact-grade gelu: A&S 7.1.26 erf (|eps|<=1.5e-7), branchless
__device__ __forceinline__ float gelu_f(float v) {
  float u = v * 0.70710678118654752f;
  float ax = fabsf(u);
  float t = __frcp_rn(1.0f + 0.3275911f * ax);
  float p = t * (0.254829592f +
           t * (-0.284496736f +
           t * (1.421413741f +
           t * (-1.453152027f +
           t * 1.061405429f))));
  float er = 1.0f - p * __expf(-u * u);
  er = copysignf(er, u);
  return 0.5f * v * (1.0f + er);
}

// ---------------- gating / prep ----------------

__global__ void k_prep(const float* __restrict__ x, ushort* __restrict__ xbf,
                       float* __restrict__ part) {
  int b = blockIdx.x, p = blockIdx.y, tid = threadIdx.x;
  const float4* xp = (const float4*)(x + ((size_t)b * Tc + (size_t)p * 128) * Cc);
  ushort4* op = (ushort4*)(xbf + ((size_t)b * Tc + (size_t)p * 128) * Cc);
  int c4 = tid & 127, r0 = tid >> 7;
  float4 s = {0.f, 0.f, 0.f, 0.f};
  for (int r = r0; r < 128; r += 2) {
    float4 v = xp[(size_t)r * 128 + c4];
    s.x += v.x; s.y += v.y; s.z += v.z; s.w += v.w;
    union { __hip_bfloat16 h[4]; ushort4 u; } cv;
    cv.h[0] = __float2bfloat16(v.x);
    cv.h[1] = __float2bfloat16(v.y);
    cv.h[2] = __float2bfloat16(v.z);
    cv.h[3] = __float2bfloat16(v.w);
    op[(size_t)r * 128 + c4] = cv.u;
  }
  __shared__ float4 sh[128];
  if (r0) sh[c4] = s;
  __syncthreads();
  if (!r0) {
    float4 o = sh[c4];
    s.x += o.x; s.y += o.y; s.z += o.z; s.w += o.w;
    ((float4*)part)[(size_t)(b * 8 + p) * 128 + c4] = s;
  }
}

__global__ void k_partial(const float* __restrict__ x, float* __restrict__ part) {
  int b = blockIdx.x, p = blockIdx.y, tid = threadIdx.x;
  const float* xp = x + ((size_t)b * Tc + (size_t)p * 128) * Cc;
  float s0 = 0.f, s1 = 0.f;
  for (int t = 0; t < 128; ++t) {
    s0 += xp[(size_t)t * Cc + tid];
    s1 += xp[(size_t)t * Cc + tid + 256];
  }
  part[(size_t)(b * 8 + p) * Cc + tid] = s0;
  part[(size_t)(b * 8 + p) * Cc + tid + 256] = s1;
}

__global__ void k_cvt_x(const float* __restrict__ src, ushort* __restrict__ dst, int n4) {
  int i = blockIdx.x * blockDim.x + threadIdx.x;
  int stride = gridDim.x * blockDim.x;
  const float4* s4 = (const float4*)src;
  ushort4* d4 = (ushort4*)dst;
  for (; i < n4; i += stride) {
    float4 v = s4[i];
    union { __hip_bfloat16 h[4]; ushort4 u; } cv;
    cv.h[0] = __float2bfloat16(v.x);
    cv.h[1] = __float2bfloat16(v.y);
    cv.h[2] = __float2bfloat16(v.z);
    cv.h[3] = __float2bfloat16(v.w);
    d4[i] = cv.u;
  }
}

__global__ void k_xg_logits(const float* __restrict__ part, const float* __restrict__ wg,
                            float* __restrict__ logits) {
  __shared__ float xg[Cc];
  __shared__ float red[Ec][4];
  int b = blockIdx.x, tid = threadIdx.x;
  for (int c = tid; c < Cc; c += 256) {
    float s = 0.f;
#pragma unroll
    for (int p = 0; p < 8; ++p) s += part[(size_t)(b * 8 + p) * Cc + c];
    xg[c] = s * (1.0f / 1024.0f);
  }
  __syncthreads();
  float le[Ec] = {0.f, 0.f, 0.f, 0.f, 0.f};
  for (int c = tid; c < Cc; c += 256) {
    float v = xg[c];
#pragma unroll
    for (int e = 0; e < Ec; ++e) le[e] += v * wg[c * Ec + e];
  }
#pragma unroll
  for (int e = 0; e < Ec; ++e) {
    float v = le[e];
#pragma unroll
    for (int off = 32; off > 0; off >>= 1) v += __shfl_down(v, off);
    if ((tid & 63) == 0) red[e][tid >> 6] = v;
  }
  __syncthreads();
  if (tid < Ec) {
    float v = red[tid][0] + red[tid][1] + red[tid][2] + red[tid][3];
    v = fminf(fmaxf(v, -50.f), 50.f);
    logits[b * Ec + tid] = v;
  }
}

__global__ void k_gate(const float* __restrict__ logits, int* __restrict__ idx,
                       float* __restrict__ loss_out) {
  __shared__ int cnt[Ec];
  int tid = threadIdx.x;
  if (tid < Ec) cnt[tid] = 0;
  __syncthreads();
  if (tid < Bc) {
    const float* lb = logits + tid * Ec;
    int best = 0;
    float bv = lb[0];
#pragma unroll
    for (int e = 1; e < Ec; ++e) {
      float v = lb[e];
      if (v > bv) { bv = v; best = e; }
    }
    idx[tid] = best;
    atomicAdd(&cnt[best], 1);
  }
  __syncthreads();
  if (tid == 0) {
    const float mean = (float)Bc / (float)Ec;
    float var = 0.f;
#pragma unroll
    for (int e = 0; e < Ec; ++e) {
      float d = (float)cnt[e] - mean;
      var += d * d;
    }
    var *= (1.0f / (Ec - 1));
    float loss = 2.f * (var / (mean * mean + 1e-10f));
    loss = fminf(fmaxf(loss, 0.f), 1000.f);
    *loss_out = loss;
  }
}

__global__ void k_transpose_cvt(const float* __restrict__ src, __hip_bfloat16* __restrict__ dst,
                                int K, int N) {
  __shared__ float tile[32][33];
  int e = blockIdx.z;
  int kb = blockIdx.y * 32, nb = blockIdx.x * 32;
  const float* s = src + (size_t)e * K * N;
  __hip_bfloat16* d = dst + (size_t)e * K * N;
  int lx = threadIdx.x & 31, ly = threadIdx.x >> 5;
#pragma unroll
  for (int r = 0; r < 4; ++r) {
    int k = kb + ly + r * 8;
    tile[ly + r * 8][lx] = s[(size_t)k * N + nb + lx];
  }
  __syncthreads();
#pragma unroll
  for (int r = 0; r < 4; ++r) {
    int n = nb + ly + r * 8;
    d[(size_t)n * K + kb + lx] = __float2bfloat16(tile[lx][ly + r * 8]);
  }
}

// =====================================================================
// 256x256 tile, BK=64, 8 waves (2M x 4N, wave-tile 128x64), dbuf LDS.
// Counted-vmcnt pipeline (T4): iter t issues S(t+1) into buf^1, then
// s_waitcnt vmcnt(8) (S(t) landed, S(t+1)'s 8 loads stay in flight),
// raw s_barrier (no drain), compute t, raw s_barrier.  LDS swizzle (T2,
// both-sides involution, verified R3) + setprio (T5).  LDS 128 KiB.
// =====================================================================

#define GEMM_PRELUDE(KDIM)                                               \
  int tid = threadIdx.x, l = tid & 63, w = tid >> 6;                     \
  int wr = w >> 2, wc = w & 3;                                           \
  const short* gA[4];                                                    \
  const short* gB[4];                                                    \
  int loff[4];                                                           \
  _Pragma("unroll")                                                      \
  for (int i = 0; i < 4; ++i) {                                          \
    int sp = i * 512 + tid;                                              \
    int r = sp >> 3;                                                     \
    int c8 = ((sp & 7) ^ (r & 7)) << 3;                                  \
    gA[i] = Ab + (size_t)r * (KDIM) + c8;                                \
    gB[i] = Bb + (size_t)r * (KDIM) + c8;                                \
    loff[i] = sp * 16;                                                   \
  }                                                                      \
  int abase = (wr * 128 + (l & 15)) * 128;                               \
  int bbase = (wc * 64 + (l & 15)) * 128;                                \
  int s0 = (((l >> 4)) ^ (l & 7)) << 4;                                  \
  int s1 = (((l >> 4) + 4) ^ (l & 7)) << 4;

#define STAGE(bi, kt)                                                    \
  {                                                                      \
    int k0_ = (kt) * 64;                                                 \
    char* da_ = (char*)&lds[bi][0][0];                                   \
    char* db_ = (char*)&lds[bi][1][0];                                   \
    _Pragma("unroll")                                                    \
    for (int i = 0; i < 4; ++i) {                                        \
      async_copy16(gA[i] + k0_, da_ + loff[i]);                          \
      async_copy16(gB[i] + k0_, db_ + loff[i]);                          \
    }                                                                    \
  }

#define COMPUTE(bi)                                                      \
  {                                                                      \
    const char* As_ = (const char*)&lds[bi][0][0];                       \
    const char* Bs_ = (const char*)&lds[bi][1][0];                       \
    __builtin_amdgcn_s_setprio(1);                                       \
    _Pragma("unroll")                                                    \
    for (int kk = 0; kk < 2; ++kk) {                                     \
      int sk = kk ? s1 : s0;                                             \
      s8_t a[8], b[4];                                                   \
      _Pragma("unroll")                                                  \
      for (int f = 0; f < 8; ++f)                                        \
        a[f] = *(const s8_t*)(As_ + abase + f * 2048 + sk);              \
      _Pragma("unroll")                                                  \
      for (int f = 0; f < 4; ++f)                                        \
        b[f] = *(const s8_t*)(Bs_ + bbase + f * 2048 + sk);              \
      _Pragma("unroll")                                                  \
      for (int fm = 0; fm < 8; ++fm)                                     \
        _Pragma("unroll")                                                \
        for (int fn = 0; fn < 4; ++fn)                                   \
          acc[fm][fn] =                                                  \
              __builtin_amdgcn_mfma_f32_16x16x32_bf16(a[fm], b[fn],      \
                                                      acc[fm][fn], 0, 0, 0); \
    }                                                                    \
    __builtin_amdgcn_s_setprio(0);                                       \
  }

#define KLOOP(NT)                                                        \
  STAGE(0, 0);                                                           \
  for (int t = 0; t < (NT) - 1; ++t) {                                   \
    STAGE((t + 1) & 1, t + 1);                                           \
    asm volatile("s_waitcnt vmcnt(8)" ::: "memory");                     \
    __builtin_amdgcn_s_barrier();                                        \
    asm volatile("" ::: "memory");                                       \
    COMPUTE(t & 1);                                                      \
    __builtin_amdgcn_s_barrier();                                        \
    asm volatile("" ::: "memory");                                       \
  }                                                                      \
  asm volatile("s_waitcnt vmcnt(0)" ::: "memory");                       \
  __builtin_amdgcn_s_barrier();                                          \
  asm volatile("" ::: "memory");                                         \
  COMPUTE(((NT) - 1) & 1);

// GEMM1: h = gelu(x @ W1[e] + b1[e]); A xbf [cb][1024][512], B w1t [E][2048][512]
__global__ __launch_bounds__(512, 2) void k_gemm1(
    const __hip_bfloat16* __restrict__ xbf, const __hip_bfloat16* __restrict__ w1t,
    const float* __restrict__ b1, const int* __restrict__ idx, int b0, int nz,
    __hip_bfloat16* __restrict__ h) {
  constexpr int K = Cc;       // 512
  constexpr int N = HIDc;     // 2048
  constexpr int NT = K / 64;  // 8
  constexpr int NBX = N / 256, NBY = Tc / 256;  // 8, 4
  __shared__ short lds[2][2][256 * 64];  // 128 KB

  int nwg = NBX * NBY * nz;
  int cpx = nwg >> 3;
  int lg = (blockIdx.x & 7) * cpx + (blockIdx.x >> 3);
  int bx = lg % NBX, by = (lg / NBX) % NBY, bz = lg / (NBX * NBY);

  int e = idx[b0 + bz];
  int m0 = by * 256, n0 = bx * 256;
  const short* Ab = (const short*)xbf + ((size_t)bz * Tc + m0) * K;
  const short* Bb = (const short*)w1t + ((size_t)e * N + n0) * K;

  GEMM_PRELUDE(K)
  f4_t acc[8][4] = {};
  KLOOP(NT)

  // epilogue: bias+gelu -> two-pass per-wave LDS transpose (stride 72)
  __syncthreads();
  short* chunk = &lds[0][0][0] + w * (64 * 72);  // 9216 B per wave
  const float* bias = b1 + (size_t)e * N;
  short* hb = (short*)(h + (size_t)bz * Tc * N);
  int cc2 = (l & 7) * 8;
#pragma unroll
  for (int p = 0; p < 2; ++p) {
#pragma unroll
    for (int fn = 0; fn < 4; ++fn) {
      float bv = bias[n0 + wc * 64 + fn * 16 + (l & 15)];
#pragma unroll
      for (int fm = 0; fm < 4; ++fm) {
        int rl = fm * 16 + ((l >> 4) << 2);
#pragma unroll
        for (int j = 0; j < 4; ++j) {
          float v = gelu_f(acc[p * 4 + fm][fn][j] + bv);
          chunk[(rl + j) * 72 + fn * 16 + (l & 15)] =
              (short)__bfloat16_as_ushort(__float2bfloat16(v));
        }
      }
    }
#pragma unroll
    for (int q = 0; q < 8; ++q) {
      int rr = q * 8 + (l >> 3);
      s8_t v = *(const s8_t*)(chunk + rr * 72 + cc2);
      *(s8_t*)(hb + (size_t)(m0 + wr * 128 + p * 64 + rr) * N + n0 + wc * 64 + cc2) = v;
    }
    // WAR fence: pass-1 LDS writes must not pass pass-0 reads
    asm volatile("s_waitcnt lgkmcnt(0)" ::: "memory");
  }
}

// GEMM2: y = h @ W2[e] + b2[e]; A h [cb][1024][2048], B w2t [E][512][2048]
__global__ __launch_bounds__(512, 2) void k_gemm2(
    const __hip_bfloat16* __restrict__ h, const __hip_bfloat16* __restrict__ w2t,
    const float* __restrict__ b2, const int* __restrict__ idx, int b0, int nz,
    float* __restrict__ out) {
  constexpr int K = HIDc;     // 2048
  constexpr int N = Cc;       // 512
  constexpr int NT = K / 64;  // 32
  constexpr int NBX = N / 256, NBY = Tc / 256;  // 2, 4
  __shared__ short lds[2][2][256 * 64];  // 128 KB

  int nwg = NBX * NBY * nz;  // 8*nz
  int cpx = nwg >> 3;
  int lg = (blockIdx.x & 7) * cpx + (blockIdx.x >> 3);
  int bx = lg % NBX, by = (lg / NBX) % NBY, bz = lg / (NBX * NBY);

  int e = idx[b0 + bz];
  int m0 = by * 256, n0 = bx * 256;
  const short* Ab = (const short*)h + ((size_t)bz * Tc + m0) * K;
  const short* Bb = (const short*)w2t + ((size_t)e * N + n0) * K;

  GEMM_PRELUDE(K)
  f4_t acc[8][4] = {};
  KLOOP(NT)

  float* ob = out + (size_t)(b0 + bz) * Tc * N;
  const float* bias = b2 + (size_t)e * N;
#pragma unroll
  for (int fn = 0; fn < 4; ++fn) {
    int col = n0 + wc * 64 + fn * 16 + (l & 15);
    float bv = bias[col];
#pragma unroll
    for (int fm = 0; fm < 8; ++fm) {
      int rbase = m0 + wr * 128 + fm * 16 + ((l >> 4) << 2);
#pragma unroll
      for (int j = 0; j < 4; ++j) {
        ob[(size_t)(rbase + j) * N + col] = acc[fm][fn][j] + bv;
      }
    }
  }
}

extern "C" void kernel_launch(void* const* d_in, const int* in_sizes, int n_in,
                              void* d_out, int out_size, void* d_ws, size_t ws_size,
                              hipStream_t stream) {
  const float* x  = (const float*)d_in[0];
  const float* wg = (const float*)d_in[1];
  const float* W1 = (const float*)d_in[2];
  const float* b1 = (const float*)d_in[3];
  const float* W2 = (const float*)d_in[4];
  const float* b2 = (const float*)d_in[5];
  float* out = (float*)d_out;

  char* ws = (char*)d_ws;
  size_t off = 0;
  float* part = (float*)(ws + off); off += (size_t)Bc * 8 * Cc * 4;
  float* logits = (float*)(ws + off); off += (size_t)Bc * Ec * 4;
  int* idx = (int*)(ws + off); off += (size_t)Bc * 4;
  off = (off + 255) & ~(size_t)255;
  __hip_bfloat16* w1t = (__hip_bfloat16*)(ws + off); off += (size_t)Ec * HIDc * Cc * 2;
  __hip_bfloat16* w2t = (__hip_bfloat16*)(ws + off); off += (size_t)Ec * HIDc * Cc * 2;
  size_t dynoff = (off + 255) & ~(size_t)255;

  const size_t x_all = (size_t)Bc * Tc * Cc * 2;   // 64 MB
  const size_t x_per_b = (size_t)Tc * Cc * 2;      // 1 MB
  const size_t h_per_b = (size_t)Tc * HIDc * 2;    // 4 MB

  k_transpose_cvt<<<dim3(HIDc / 32, Cc / 32, Ec), 256, 0, stream>>>(W1, w1t, Cc, HIDc);
  k_transpose_cvt<<<dim3(Cc / 32, HIDc / 32, Ec), 256, 0, stream>>>(W2, w2t, HIDc, Cc);

  if (ws_size >= dynoff + x_all + h_per_b) {
    __hip_bfloat16* xbf = (__hip_bfloat16*)(ws + dynoff);
    __hip_bfloat16* hbf = (__hip_bfloat16*)(ws + dynoff + x_all);
    int cb = (int)((ws_size - dynoff - x_all) / h_per_b);
    if (cb > Bc) cb = Bc;

    k_prep<<<dim3(Bc, 8), 256, 0, stream>>>(x, (ushort*)xbf, part);
    k_xg_logits<<<dim3(Bc), 256, 0, stream>>>(part, wg, logits);
    k_gate<<<dim3(1), 256, 0, stream>>>(logits, idx, out + ((size_t)out_size - 1));

    for (int b0 = 0; b0 < Bc; b0 += cb) {
      int c = (Bc - b0) < cb ? (Bc - b0) : cb;
      const __hip_bfloat16* xc = xbf + (size_t)b0 * Tc * Cc;
      k_gemm1<<<dim3((HIDc / 256) * (Tc / 256) * c), 512, 0, stream>>>(
          xc, w1t, b1, idx, b0, c, hbf);
      k_gemm2<<<dim3((Cc / 256) * (Tc / 256) * c), 512, 0, stream>>>(
          hbf, w2t, b2, idx, b0, c, out);
    }
  } else {
    size_t avail = ws_size > dynoff ? ws_size - dynoff : 0;
    int cb = (int)(avail / (x_per_b + h_per_b));
    if (cb > Bc) cb = Bc;
    if (cb < 1) cb = 1;
    __hip_bfloat16* xbf = (__hip_bfloat16*)(ws + dynoff);
    __hip_bfloat16* hbf = (__hip_bfloat16*)(ws + dynoff + (size_t)cb * x_per_b);

    k_partial<<<dim3(Bc, 8), 256, 0, stream>>>(x, part);
    k_xg_logits<<<dim3(Bc), 256, 0, stream>>>(part, wg, logits);
    k_gate<<<dim3(1), 256, 0, stream>>>(logits, idx, out + ((size_t)out_size - 1));

    for (int b0 = 0; b0 < Bc; b0 += cb) {
      int c = (Bc - b0) < cb ? (Bc - b0) : cb;
      int n4 = c * (Tc * Cc / 4);
      k_cvt_x<<<dim3(1024), 256, 0, stream>>>(x + (size_t)b0 * Tc * Cc, (ushort*)xbf, n4);
      k_gemm1<<<dim3((HIDc / 256) * (Tc / 256) * c), 512, 0, stream>>>(
          xbf, w1t, b1, idx, b0, c, hbf);
      k_gemm2<<<dim3((Cc / 256) * (Tc / 256) * c), 512, 0, stream>>>(
          hbf, w2t, b2, idx, b0, c, out);
    }
  }
}

// Round 6
// 471.673 us; speedup vs baseline: 1.4497x; 1.0271x over previous
//
#include <hip/hip_runtime.h>
#include <hip/hip_bf16.h>
#include <math.h>

typedef __attribute__((ext_vector_type(4))) float f4_t;
typedef __attribute__((ext_vector_type(8))) short s8_t;

constexpr int Bc = 64;      // batches
constexpr int Tc = 1024;    // tokens per batch (H*W)
constexpr int Cc = 512;     // channels
constexpr int Ec = 5;       // experts
constexpr int HIDc = 2048;  // hidden

// async global->LDS, 16B per lane (linear LDS dest: wave-uniform base + lane*16)
__device__ __forceinline__ void async_copy16(const void* gsrc, void* ldst) {
  __builtin_amdgcn_global_load_lds(
      (const __attribute__((address_space(1))) unsigned int*)gsrc,
      (__attribute__((address_space(3))) unsigned int*)ldst, 16, 0, 0);
}

// exact-grade gelu: A&S 7.1.26 erf (|eps|<=1.5e-7), branchless
__device__ __forceinline__ float gelu_f(float v) {
  float u = v * 0.70710678118654752f;
  float ax = fabsf(u);
  float t = __frcp_rn(1.0f + 0.3275911f * ax);
  float p = t * (0.254829592f +
           t * (-0.284496736f +
           t * (1.421413741f +
           t * (-1.453152027f +
           t * 1.061405429f))));
  float er = 1.0f - p * __expf(-u * u);
  er = copysignf(er, u);
  return 0.5f * v * (1.0f + er);
}

// ---------------- gating / prep ----------------

__global__ void k_prep(const float* __restrict__ x, ushort* __restrict__ xbf,
                       float* __restrict__ part) {
  int b = blockIdx.x, p = blockIdx.y, tid = threadIdx.x;
  const float4* xp = (const float4*)(x + ((size_t)b * Tc + (size_t)p * 128) * Cc);
  ushort4* op = (ushort4*)(xbf + ((size_t)b * Tc + (size_t)p * 128) * Cc);
  int c4 = tid & 127, r0 = tid >> 7;
  float4 s = {0.f, 0.f, 0.f, 0.f};
  for (int r = r0; r < 128; r += 2) {
    float4 v = xp[(size_t)r * 128 + c4];
    s.x += v.x; s.y += v.y; s.z += v.z; s.w += v.w;
    union { __hip_bfloat16 h[4]; ushort4 u; } cv;
    cv.h[0] = __float2bfloat16(v.x);
    cv.h[1] = __float2bfloat16(v.y);
    cv.h[2] = __float2bfloat16(v.z);
    cv.h[3] = __float2bfloat16(v.w);
    op[(size_t)r * 128 + c4] = cv.u;
  }
  __shared__ float4 sh[128];
  if (r0) sh[c4] = s;
  __syncthreads();
  if (!r0) {
    float4 o = sh[c4];
    s.x += o.x; s.y += o.y; s.z += o.z; s.w += o.w;
    ((float4*)part)[(size_t)(b * 8 + p) * 128 + c4] = s;
  }
}

__global__ void k_partial(const float* __restrict__ x, float* __restrict__ part) {
  int b = blockIdx.x, p = blockIdx.y, tid = threadIdx.x;
  const float* xp = x + ((size_t)b * Tc + (size_t)p * 128) * Cc;
  float s0 = 0.f, s1 = 0.f;
  for (int t = 0; t < 128; ++t) {
    s0 += xp[(size_t)t * Cc + tid];
    s1 += xp[(size_t)t * Cc + tid + 256];
  }
  part[(size_t)(b * 8 + p) * Cc + tid] = s0;
  part[(size_t)(b * 8 + p) * Cc + tid + 256] = s1;
}

__global__ void k_cvt_x(const float* __restrict__ src, ushort* __restrict__ dst, int n4) {
  int i = blockIdx.x * blockDim.x + threadIdx.x;
  int stride = gridDim.x * blockDim.x;
  const float4* s4 = (const float4*)src;
  ushort4* d4 = (ushort4*)dst;
  for (; i < n4; i += stride) {
    float4 v = s4[i];
    union { __hip_bfloat16 h[4]; ushort4 u; } cv;
    cv.h[0] = __float2bfloat16(v.x);
    cv.h[1] = __float2bfloat16(v.y);
    cv.h[2] = __float2bfloat16(v.z);
    cv.h[3] = __float2bfloat16(v.w);
    d4[i] = cv.u;
  }
}

__global__ void k_xg_logits(const float* __restrict__ part, const float* __restrict__ wg,
                            float* __restrict__ logits) {
  __shared__ float xg[Cc];
  __shared__ float red[Ec][4];
  int b = blockIdx.x, tid = threadIdx.x;
  for (int c = tid; c < Cc; c += 256) {
    float s = 0.f;
#pragma unroll
    for (int p = 0; p < 8; ++p) s += part[(size_t)(b * 8 + p) * Cc + c];
    xg[c] = s * (1.0f / 1024.0f);
  }
  __syncthreads();
  float le[Ec] = {0.f, 0.f, 0.f, 0.f, 0.f};
  for (int c = tid; c < Cc; c += 256) {
    float v = xg[c];
#pragma unroll
    for (int e = 0; e < Ec; ++e) le[e] += v * wg[c * Ec + e];
  }
#pragma unroll
  for (int e = 0; e < Ec; ++e) {
    float v = le[e];
#pragma unroll
    for (int off = 32; off > 0; off >>= 1) v += __shfl_down(v, off);
    if ((tid & 63) == 0) red[e][tid >> 6] = v;
  }
  __syncthreads();
  if (tid < Ec) {
    float v = red[tid][0] + red[tid][1] + red[tid][2] + red[tid][3];
    v = fminf(fmaxf(v, -50.f), 50.f);
    logits[b * Ec + tid] = v;
  }
}

__global__ void k_gate(const float* __restrict__ logits, int* __restrict__ idx,
                       float* __restrict__ loss_out) {
  __shared__ int cnt[Ec];
  int tid = threadIdx.x;
  if (tid < Ec) cnt[tid] = 0;
  __syncthreads();
  if (tid < Bc) {
    const float* lb = logits + tid * Ec;
    int best = 0;
    float bv = lb[0];
#pragma unroll
    for (int e = 1; e < Ec; ++e) {
      float v = lb[e];
      if (v > bv) { bv = v; best = e; }
    }
    idx[tid] = best;
    atomicAdd(&cnt[best], 1);
  }
  __syncthreads();
  if (tid == 0) {
    const float mean = (float)Bc / (float)Ec;
    float var = 0.f;
#pragma unroll
    for (int e = 0; e < Ec; ++e) {
      float d = (float)cnt[e] - mean;
      var += d * d;
    }
    var *= (1.0f / (Ec - 1));
    float loss = 2.f * (var / (mean * mean + 1e-10f));
    loss = fminf(fmaxf(loss, 0.f), 1000.f);
    *loss_out = loss;
  }
}

__global__ void k_transpose_cvt(const float* __restrict__ src, __hip_bfloat16* __restrict__ dst,
                                int K, int N) {
  __shared__ float tile[32][33];
  int e = blockIdx.z;
  int kb = blockIdx.y * 32, nb = blockIdx.x * 32;
  const float* s = src + (size_t)e * K * N;
  __hip_bfloat16* d = dst + (size_t)e * K * N;
  int lx = threadIdx.x & 31, ly = threadIdx.x >> 5;
#pragma unroll
  for (int r = 0; r < 4; ++r) {
    int k = kb + ly + r * 8;
    tile[ly + r * 8][lx] = s[(size_t)k * N + nb + lx];
  }
  __syncthreads();
#pragma unroll
  for (int r = 0; r < 4; ++r) {
    int n = nb + ly + r * 8;
    d[(size_t)n * K + kb + lx] = __float2bfloat16(tile[lx][ly + r * 8]);
  }
}

// =====================================================================
// 256x256 tile, BK=64, 8 waves (2M x 4N, wave-tile 128x64), dbuf LDS,
// T2 both-sides swizzle.  4-PHASE interleave per K-step (m201 pattern):
// phase p = {ds_read subtile || stage loads (p=0,1)} -> setprio + 16 MFMA
// -> s_barrier.  Stage loads for step t+1 issue in phases 0-1 of step t,
// so the end-of-step vmcnt(0) finds them already landed (~2 phases of
// cover).  Barrier hazard points identical to the R4 race-screened
// structure (superset of barriers).  LDS 128 KiB.
// =====================================================================

#define GEMM_PRELUDE(KDIM)                                               \
  int tid = threadIdx.x, l = tid & 63, w = tid >> 6;                     \
  int wr = w >> 2, wc = w & 3;                                           \
  const short* gA[4];                                                    \
  const short* gB[4];                                                    \
  int loff[4];                                                           \
  _Pragma("unroll")                                                      \
  for (int i = 0; i < 4; ++i) {                                          \
    int sp = i * 512 + tid;                                              \
    int r = sp >> 3;                                                     \
    int c8 = ((sp & 7) ^ (r & 7)) << 3;                                  \
    gA[i] = Ab + (size_t)r * (KDIM) + c8;                                \
    gB[i] = Bb + (size_t)r * (KDIM) + c8;                                \
    loff[i] = sp * 16;                                                   \
  }                                                                      \
  int abase = (wr * 128 + (l & 15)) * 128;                               \
  int bbase = (wc * 64 + (l & 15)) * 128;                                \
  int s0 = (((l >> 4)) ^ (l & 7)) << 4;                                  \
  int s1 = (((l >> 4) + 4) ^ (l & 7)) << 4;

#define STAGE_A(bi, kt)                                                  \
  {                                                                      \
    int k0_ = (kt) * 64;                                                 \
    char* d_ = (char*)&lds[bi][0][0];                                    \
    _Pragma("unroll")                                                    \
    for (int i = 0; i < 4; ++i) async_copy16(gA[i] + k0_, d_ + loff[i]); \
  }
#define STAGE_B(bi, kt)                                                  \
  {                                                                      \
    int k0_ = (kt) * 64;                                                 \
    char* d_ = (char*)&lds[bi][1][0];                                    \
    _Pragma("unroll")                                                    \
    for (int i = 0; i < 4; ++i) async_copy16(gB[i] + k0_, d_ + loff[i]); \
  }

#define BAR()                          \
  __builtin_amdgcn_s_barrier();        \
  asm volatile("" ::: "memory")

// phase p: read A-quad (fm = 2p, 2p+1), fire 16 MFMA
#define MPHASE(p)                                                            \
  _Pragma("unroll")                                                          \
  for (int j = 0; j < 2; ++j) {                                              \
    afr[j * 2 + 0] = *(const s8_t*)(As_ + abase + ((p) * 2 + j) * 2048 + s0);\
    afr[j * 2 + 1] = *(const s8_t*)(As_ + abase + ((p) * 2 + j) * 2048 + s1);\
  }                                                                          \
  __builtin_amdgcn_s_setprio(1);                                             \
  _Pragma("unroll")                                                          \
  for (int kk = 0; kk < 2; ++kk)                                             \
    _Pragma("unroll")                                                        \
    for (int j = 0; j < 2; ++j)                                              \
      _Pragma("unroll")                                                      \
      for (int fn = 0; fn < 4; ++fn)                                         \
        acc[(p) * 2 + j][fn] = __builtin_amdgcn_mfma_f32_16x16x32_bf16(      \
            afr[j * 2 + kk], bfr[fn * 2 + kk], acc[(p) * 2 + j][fn], 0, 0, 0);\
  __builtin_amdgcn_s_setprio(0);

#define KSTEP(c, t, NT)                                                  \
  {                                                                      \
    const char* As_ = (const char*)&lds[c][0][0];                        \
    const char* Bs_ = (const char*)&lds[c][1][0];                        \
    s8_t bfr[8], afr[4];                                                 \
    /* phase 0: stage A(t+1) || read all B + A-quad0 */                  \
    if ((t) + 1 < (NT)) STAGE_A((c) ^ 1, (t) + 1);                       \
    _Pragma("unroll")                                                    \
    for (int fn = 0; fn < 4; ++fn) {                                     \
      bfr[fn * 2 + 0] = *(const s8_t*)(Bs_ + bbase + fn * 2048 + s0);    \
      bfr[fn * 2 + 1] = *(const s8_t*)(Bs_ + bbase + fn * 2048 + s1);    \
    }                                                                    \
    MPHASE(0)                                                            \
    BAR();                                                               \
    /* phase 1: stage B(t+1) || A-quad1 */                               \
    if ((t) + 1 < (NT)) STAGE_B((c) ^ 1, (t) + 1);                       \
    MPHASE(1)                                                            \
    BAR();                                                               \
    MPHASE(2)                                                            \
    BAR();                                                               \
    MPHASE(3)                                                            \
    if ((t) + 1 < (NT)) { asm volatile("s_waitcnt vmcnt(0)" ::: "memory"); } \
    BAR();                                                               \
  }

// GEMM1: h = gelu(x @ W1[e] + b1[e]); A xbf [cb][1024][512], B w1t [E][2048][512]
__global__ __launch_bounds__(512, 2) void k_gemm1(
    const __hip_bfloat16* __restrict__ xbf, const __hip_bfloat16* __restrict__ w1t,
    const float* __restrict__ b1, const int* __restrict__ idx, int b0, int nz,
    __hip_bfloat16* __restrict__ h) {
  constexpr int K = Cc;       // 512
  constexpr int N = HIDc;     // 2048
  constexpr int NT = K / 64;  // 8
  constexpr int NBX = N / 256, NBY = Tc / 256;  // 8, 4
  __shared__ short lds[2][2][256 * 64];  // 128 KB

  int nwg = NBX * NBY * nz;
  int cpx = nwg >> 3;
  int lg = (blockIdx.x & 7) * cpx + (blockIdx.x >> 3);
  int bx = lg % NBX, by = (lg / NBX) % NBY, bz = lg / (NBX * NBY);

  int e = idx[b0 + bz];
  int m0 = by * 256, n0 = bx * 256;
  const short* Ab = (const short*)xbf + ((size_t)bz * Tc + m0) * K;
  const short* Bb = (const short*)w1t + ((size_t)e * N + n0) * K;

  GEMM_PRELUDE(K)
  f4_t acc[8][4] = {};

  STAGE_A(0, 0);
  STAGE_B(0, 0);
  asm volatile("s_waitcnt vmcnt(0)" ::: "memory");
  BAR();
  for (int t = 0; t < NT; ++t) {
    KSTEP(t & 1, t, NT)
  }

  // epilogue: bias+gelu -> two-pass per-wave LDS transpose (stride 72)
  __syncthreads();
  short* chunk = &lds[0][0][0] + w * (64 * 72);  // 9216 B per wave
  const float* bias = b1 + (size_t)e * N;
  short* hb = (short*)(h + (size_t)bz * Tc * N);
  int cc2 = (l & 7) * 8;
#pragma unroll
  for (int p = 0; p < 2; ++p) {
#pragma unroll
    for (int fn = 0; fn < 4; ++fn) {
      float bv = bias[n0 + wc * 64 + fn * 16 + (l & 15)];
#pragma unroll
      for (int fm = 0; fm < 4; ++fm) {
        int rl = fm * 16 + ((l >> 4) << 2);
#pragma unroll
        for (int j = 0; j < 4; ++j) {
          float v = gelu_f(acc[p * 4 + fm][fn][j] + bv);
          chunk[(rl + j) * 72 + fn * 16 + (l & 15)] =
              (short)__bfloat16_as_ushort(__float2bfloat16(v));
        }
      }
    }
#pragma unroll
    for (int q = 0; q < 8; ++q) {
      int rr = q * 8 + (l >> 3);
      s8_t v = *(const s8_t*)(chunk + rr * 72 + cc2);
      *(s8_t*)(hb + (size_t)(m0 + wr * 128 + p * 64 + rr) * N + n0 + wc * 64 + cc2) = v;
    }
    // WAR fence: pass-1 LDS writes must not pass pass-0 reads
    asm volatile("s_waitcnt lgkmcnt(0)" ::: "memory");
  }
}

// GEMM2: y = h @ W2[e] + b2[e]; A h [cb][1024][2048], B w2t [E][512][2048]
__global__ __launch_bounds__(512, 2) void k_gemm2(
    const __hip_bfloat16* __restrict__ h, const __hip_bfloat16* __restrict__ w2t,
    const float* __restrict__ b2, const int* __restrict__ idx, int b0, int nz,
    float* __restrict__ out) {
  constexpr int K = HIDc;     // 2048
  constexpr int N = Cc;       // 512
  constexpr int NT = K / 64;  // 32
  constexpr int NBX = N / 256, NBY = Tc / 256;  // 2, 4
  __shared__ short lds[2][2][256 * 64];  // 128 KB

  int nwg = NBX * NBY * nz;  // 8*nz
  int cpx = nwg >> 3;
  int lg = (blockIdx.x & 7) * cpx + (blockIdx.x >> 3);
  int bx = lg % NBX, by = (lg / NBX) % NBY, bz = lg / (NBX * NBY);

  int e = idx[b0 + bz];
  int m0 = by * 256, n0 = bx * 256;
  const short* Ab = (const short*)h + ((size_t)bz * Tc + m0) * K;
  const short* Bb = (const short*)w2t + ((size_t)e * N + n0) * K;

  GEMM_PRELUDE(K)
  f4_t acc[8][4] = {};

  STAGE_A(0, 0);
  STAGE_B(0, 0);
  asm volatile("s_waitcnt vmcnt(0)" ::: "memory");
  BAR();
  for (int t = 0; t < NT; ++t) {
    KSTEP(t & 1, t, NT)
  }

  float* ob = out + (size_t)(b0 + bz) * Tc * N;
  const float* bias = b2 + (size_t)e * N;
#pragma unroll
  for (int fn = 0; fn < 4; ++fn) {
    int col = n0 + wc * 64 + fn * 16 + (l & 15);
    float bv = bias[col];
#pragma unroll
    for (int fm = 0; fm < 8; ++fm) {
      int rbase = m0 + wr * 128 + fm * 16 + ((l >> 4) << 2);
#pragma unroll
      for (int j = 0; j < 4; ++j) {
        ob[(size_t)(rbase + j) * N + col] = acc[fm][fn][j] + bv;
      }
    }
  }
}

extern "C" void kernel_launch(void* const* d_in, const int* in_sizes, int n_in,
                              void* d_out, int out_size, void* d_ws, size_t ws_size,
                              hipStream_t stream) {
  const float* x  = (const float*)d_in[0];
  const float* wg = (const float*)d_in[1];
  const float* W1 = (const float*)d_in[2];
  const float* b1 = (const float*)d_in[3];
  const float* W2 = (const float*)d_in[4];
  const float* b2 = (const float*)d_in[5];
  float* out = (float*)d_out;

  char* ws = (char*)d_ws;
  size_t off = 0;
  float* part = (float*)(ws + off); off += (size_t)Bc * 8 * Cc * 4;
  float* logits = (float*)(ws + off); off += (size_t)Bc * Ec * 4;
  int* idx = (int*)(ws + off); off += (size_t)Bc * 4;
  off = (off + 255) & ~(size_t)255;
  __hip_bfloat16* w1t = (__hip_bfloat16*)(ws + off); off += (size_t)Ec * HIDc * Cc * 2;
  __hip_bfloat16* w2t = (__hip_bfloat16*)(ws + off); off += (size_t)Ec * HIDc * Cc * 2;
  size_t dynoff = (off + 255) & ~(size_t)255;

  const size_t x_all = (size_t)Bc * Tc * Cc * 2;   // 64 MB
  const size_t x_per_b = (size_t)Tc * Cc * 2;      // 1 MB
  const size_t h_per_b = (size_t)Tc * HIDc * 2;    // 4 MB

  k_transpose_cvt<<<dim3(HIDc / 32, Cc / 32, Ec), 256, 0, stream>>>(W1, w1t, Cc, HIDc);
  k_transpose_cvt<<<dim3(Cc / 32, HIDc / 32, Ec), 256, 0, stream>>>(W2, w2t, HIDc, Cc);

  if (ws_size >= dynoff + x_all + h_per_b) {
    __hip_bfloat16* xbf = (__hip_bfloat16*)(ws + dynoff);
    __hip_bfloat16* hbf = (__hip_bfloat16*)(ws + dynoff + x_all);
    int cb = (int)((ws_size - dynoff - x_all) / h_per_b);
    if (cb > Bc) cb = Bc;

    k_prep<<<dim3(Bc, 8), 256, 0, stream>>>(x, (ushort*)xbf, part);
    k_xg_logits<<<dim3(Bc), 256, 0, stream>>>(part, wg, logits);
    k_gate<<<dim3(1), 256, 0, stream>>>(logits, idx, out + ((size_t)out_size - 1));

    for (int b0 = 0; b0 < Bc; b0 += cb) {
      int c = (Bc - b0) < cb ? (Bc - b0) : cb;
      const __hip_bfloat16* xc = xbf + (size_t)b0 * Tc * Cc;
      k_gemm1<<<dim3((HIDc / 256) * (Tc / 256) * c), 512, 0, stream>>>(
          xc, w1t, b1, idx, b0, c, hbf);
      k_gemm2<<<dim3((Cc / 256) * (Tc / 256) * c), 512, 0, stream>>>(
          hbf, w2t, b2, idx, b0, c, out);
    }
  } else {
    size_t avail = ws_size > dynoff ? ws_size - dynoff : 0;
    int cb = (int)(avail / (x_per_b + h_per_b));
    if (cb > Bc) cb = Bc;
    if (cb < 1) cb = 1;
    __hip_bfloat16* xbf = (__hip_bfloat16*)(ws + dynoff);
    __hip_bfloat16* hbf = (__hip_bfloat16*)(ws + dynoff + (size_t)cb * x_per_b);

    k_partial<<<dim3(Bc, 8), 256, 0, stream>>>(x, part);
    k_xg_logits<<<dim3(Bc), 256, 0, stream>>>(part, wg, logits);
    k_gate<<<dim3(1), 256, 0, stream>>>(logits, idx, out + ((size_t)out_size - 1));

    for (int b0 = 0; b0 < Bc; b0 += cb) {
      int c = (Bc - b0) < cb ? (Bc - b0) : cb;
      int n4 = c * (Tc * Cc / 4);
      k_cvt_x<<<dim3(1024), 256, 0, stream>>>(x + (size_t)b0 * Tc * Cc, (ushort*)xbf, n4);
      k_gemm1<<<dim3((HIDc / 256) * (Tc / 256) * c), 512, 0, stream>>>(
          xbf, w1t, b1, idx, b0, c, hbf);
      k_gemm2<<<dim3((Cc / 256) * (Tc / 256) * c), 512, 0, stream>>>(
          hbf, w2t, b2, idx, b0, c, out);
    }
  }
}